// Round 3
// baseline (7219.373 us; speedup 1.0000x reference)
//
#include <hip/hip_runtime.h>
#include <hip/hip_bf16.h>

typedef short short8 __attribute__((ext_vector_type(8)));
typedef float floatx4 __attribute__((ext_vector_type(4)));
typedef int   int4v  __attribute__((ext_vector_type(4)));

constexpr int BB = 64, PP = 196, CENC = 2048, HH = 512, AA = 512, EE = 512;
constexpr int VV = 10000, TT = 20, TM1 = 19;
constexpr int NBLK = 256;   // persistent kernel grid

__device__ __forceinline__ float bf2f(short u) {
    union { unsigned u; float f; } v; v.u = ((unsigned)(unsigned short)u) << 16; return v.f;
}
__device__ __forceinline__ short f2bf(float f) {
    union { float f; unsigned u; } v; v.f = f;
    unsigned r = v.u + 0x7FFF + ((v.u >> 16) & 1);
    return (short)(r >> 16);
}

// Device-scope grid barrier: bar[0]=arrive counter, bar[32]=generation (split lines).
// Self-resetting; bar memset to 0 at the start of every kernel_launch.
__device__ __forceinline__ void gridBarrier(unsigned* bar)
{
    __threadfence();
    __syncthreads();
    if (threadIdx.x == 0) {
        unsigned g = __hip_atomic_load(&bar[32], __ATOMIC_RELAXED, __HIP_MEMORY_SCOPE_AGENT);
        unsigned a = __hip_atomic_fetch_add(&bar[0], 1u, __ATOMIC_ACQ_REL, __HIP_MEMORY_SCOPE_AGENT);
        if (a == (unsigned)(NBLK - 1)) {
            __hip_atomic_store(&bar[0], 0u, __ATOMIC_RELAXED, __HIP_MEMORY_SCOPE_AGENT);
            __hip_atomic_fetch_add(&bar[32], 1u, __ATOMIC_RELEASE, __HIP_MEMORY_SCOPE_AGENT);
        } else {
            while (__hip_atomic_load(&bar[32], __ATOMIC_ACQUIRE, __HIP_MEMORY_SCOPE_AGENT) == g)
                __builtin_amdgcn_s_sleep(2);
        }
    }
    __syncthreads();
    __threadfence();
}

// ---------------------------------------------------------------------------
// Weight prep: f32 -> bf16 conversions + concatenations + bias builds.
// ---------------------------------------------------------------------------
__global__ __launch_bounds__(256)
void kPrepW(const float* __restrict__ encw_s, const float* __restrict__ haw,
            const float* __restrict__ fbw, const float* __restrict__ whh,
            const float* __restrict__ wih, const float* __restrict__ fcw,
            const float* __restrict__ hab, const float* __restrict__ fbb,
            const float* __restrict__ bih, const float* __restrict__ bhh,
            short* __restrict__ encw_d, short* __restrict__ wcat_d,
            short* __restrict__ wihe_d, short* __restrict__ wihm_d,
            short* __restrict__ fc_d, float* __restrict__ biascat,
            float* __restrict__ biasg)
{
    long idx = (long)blockIdx.x * 256 + threadIdx.x;
    long e = idx * 8;
    const float* sp = nullptr; short* dp = nullptr; long de = 0;
    if (e < 1048576)       { sp = &encw_s[e]; dp = encw_d; de = e; }
    else if (e < 3407872)  { long u = e - 1048576; long row = u >> 9, col = u & 511;
                             sp = (row < 512) ? &haw[row * 512 + col]
                                : (row < 2560) ? &fbw[(row - 512) * 512 + col]
                                               : &whh[(row - 2560) * 512 + col];
                             dp = wcat_d; de = u; }
    else if (e < 7602176)  { long u = e - 3407872; long row = u >> 11, col = u & 2047;
                             sp = &wih[row * 2560 + 512 + col]; dp = wihe_d; de = u; }
    else if (e < 8650752)  { long u = e - 7602176; long row = u >> 9, col = u & 511;
                             sp = &wih[row * 2560 + col]; dp = wihm_d; de = u; }
    else if (e < 13770752) { long u = e - 8650752; sp = &fcw[u]; dp = fc_d; de = u; }
    else if (e < 13775360) { long u = e - 13770752;
                             for (int j = 0; j < 8; ++j) { long w = u + j;
                                 biascat[w] = (w < 512) ? hab[w] : ((w < 2560) ? fbb[w - 512] : 0.f); }
                             return; }
    else if (e < 13777408) { long u = e - 13775360;
                             for (int j = 0; j < 8; ++j) biasg[u + j] = bih[u + j] + bhh[u + j];
                             return; }
    else return;
    union { short s[8]; int4v v; } u8;
    #pragma unroll
    for (int j = 0; j < 8; ++j) u8.s[j] = f2bf(sp[j]);
    *reinterpret_cast<int4v*>(&dp[de]) = u8.v;
}

// Fused: mean over P + enc f32->bf16 (single pass over enc). grid (64,8).
template<int FULL>
__global__ __launch_bounds__(256)
void kMeanEnc(const float* __restrict__ enc, short* __restrict__ enc16,
              float* __restrict__ mean)
{
    int b = blockIdx.x;
    int k = blockIdx.y * 256 + threadIdx.x;
    const float* eb = &enc[(size_t)b * PP * CENC + k];
    short* ob = &enc16[(size_t)b * PP * CENC + k];
    float s0 = 0, s1 = 0, s2 = 0, s3 = 0;
    for (int p = 0; p < PP; p += 4) {   // 196 = 4*49, no tail
        float v0 = eb[(size_t)(p + 0) * CENC], v1 = eb[(size_t)(p + 1) * CENC];
        float v2 = eb[(size_t)(p + 2) * CENC], v3 = eb[(size_t)(p + 3) * CENC];
        s0 += v0; s1 += v1; s2 += v2; s3 += v3;
        if (FULL) {
            ob[(size_t)(p + 0) * CENC] = f2bf(v0); ob[(size_t)(p + 1) * CENC] = f2bf(v1);
            ob[(size_t)(p + 2) * CENC] = f2bf(v2); ob[(size_t)(p + 3) * CENC] = f2bf(v3);
        }
    }
    mean[b * CENC + k] = ((s0 + s1) + (s2 + s3)) * (1.0f / PP);
}

// embedding gather -> embA[r = t*64+b][512] bf16
__global__ __launch_bounds__(256)
void kEmbGather(const float* __restrict__ embw, const int* __restrict__ captions,
                short* __restrict__ embA)
{
    long e = ((long)blockIdx.x * 256 + threadIdx.x) * 8;
    int r = (int)(e >> 9), j = (int)(e & 511);
    int t = r >> 6, b = r & 63;
    int tok = captions[b * TT + t];
    const float* sp = &embw[(size_t)tok * EE + j];
    union { short s[8]; int4v v; } u8;
    #pragma unroll
    for (int q = 0; q < 8; ++q) u8.s[q] = f2bf(sp[q]);
    *reinterpret_cast<int4v*>(&embA[e]) = u8.v;
}

// ---------------------------------------------------------------------------
// MFMA bf16 GEMM (precompute/epilogue GEMMs): C[M,N] = A[M,K] @ W[N,K]^T.
// ---------------------------------------------------------------------------
template<int AOP, int EOP, int SWZ>
__global__ __launch_bounds__(256)
void kGemm(const void* __restrict__ Ap, int lda, const short* __restrict__ W, int ldw,
           const float* __restrict__ bias, int Ntot,
           float* __restrict__ outF, int ldc, short* __restrict__ outB,
           int nk, const int* __restrict__ lengths)
{
    __shared__ short As[64 * 64];
    __shared__ short Ws[64 * 64];
    int nb, mb, kz;
    if (SWZ == 0) { nb = blockIdx.x; mb = blockIdx.y; kz = blockIdx.z; }
    else if (SWZ == 1) {  // att1: 1568 blocks, group 8 same-A n-blocks per XCD
        int j = blockIdx.x;
        if (j < 1536) { mb = (j >> 6) * 8 + (j & 7); nb = (j >> 3) & 7; }
        else          { int u = j - 1536; mb = 192 + (u >> 3); nb = u & 7; }
        kz = 0;
    } else {              // pred: 3040 blocks
        int j = blockIdx.x; int c = j & 7, s = j >> 3;
        mb = s % 19; int u = s / 19; nb = 8 * u + c; kz = 0;
        if (nb * 64 >= Ntot) return;
    }
    const int tid = threadIdx.x;
    const int m0 = mb * 64, n0 = nb * 64, k0 = kz * nk * 64;
    const int w = tid >> 6, l = tid & 63;
    floatx4 acc[4] = {};

    for (int ks = 0; ks < nk; ++ks) {
        int kt = k0 + ks * 64;
        if (AOP == 0) {
            const short* A = (const short*)Ap;
            #pragma unroll
            for (int i = 0; i < 2; ++i) {
                int s = tid + i * 256, row = s >> 3, cg = s & 7;
                int4v v = *reinterpret_cast<const int4v*>(&A[(size_t)(m0 + row) * lda + kt + cg * 8]);
                *reinterpret_cast<int4v*>(&As[row * 64 + ((cg ^ (row & 7)) << 3)]) = v;
            }
        } else {
            const float* A = (const float*)Ap;
            #pragma unroll
            for (int i = 0; i < 2; ++i) {
                int s = tid + i * 256, row = s >> 3, cg = s & 7;
                const float* sp = &A[(size_t)(m0 + row) * lda + kt + cg * 8];
                float4 a = *reinterpret_cast<const float4*>(sp);
                float4 b = *reinterpret_cast<const float4*>(sp + 4);
                union { short s[8]; int4v v; } u8;
                u8.s[0]=f2bf(a.x); u8.s[1]=f2bf(a.y); u8.s[2]=f2bf(a.z); u8.s[3]=f2bf(a.w);
                u8.s[4]=f2bf(b.x); u8.s[5]=f2bf(b.y); u8.s[6]=f2bf(b.z); u8.s[7]=f2bf(b.w);
                *reinterpret_cast<int4v*>(&As[row * 64 + ((cg ^ (row & 7)) << 3)]) = u8.v;
            }
        }
        #pragma unroll
        for (int i = 0; i < 2; ++i) {
            int s = tid + i * 256, r = s >> 3, cg = s & 7;
            int4v v = {0, 0, 0, 0};
            int wr = n0 + r;
            if (wr < Ntot)
                v = *reinterpret_cast<const int4v*>(&W[(size_t)wr * ldw + kt + cg * 8]);
            *reinterpret_cast<int4v*>(&Ws[r * 64 + ((cg ^ (r & 7)) << 3)]) = v;
        }
        __syncthreads();
        #pragma unroll
        for (int kc = 0; kc < 2; ++kc) {
            int arow = 16 * w + (l & 15);
            int cg = 4 * kc + (l >> 4);
            short8 af = *reinterpret_cast<const short8*>(&As[arow * 64 + ((cg ^ (arow & 7)) << 3)]);
            #pragma unroll
            for (int q = 0; q < 4; ++q) {
                int wrow = 16 * q + (l & 15);
                short8 wf = *reinterpret_cast<const short8*>(&Ws[wrow * 64 + ((cg ^ (wrow & 7)) << 3)]);
                acc[q] = __builtin_amdgcn_mfma_f32_16x16x32_bf16(af, wf, acc[q], 0, 0, 0);
            }
        }
        __syncthreads();
    }
    int l4 = l >> 4, l15 = l & 15;
    #pragma unroll
    for (int q = 0; q < 4; ++q) {
        #pragma unroll
        for (int j = 0; j < 4; ++j) {
            int m = m0 + 16 * w + 4 * l4 + j;
            int n = n0 + 16 * q + l15;
            float val = acc[q][j];
            if (EOP == 0) {
                outF[(size_t)m * ldc + n] = val + bias[n];
            } else if (EOP == 1) {
                outB[(size_t)m * ldc + n] = f2bf(val + bias[n]);
            } else { // pred
                if (n < Ntot) {
                    int b = m & 63, tt = m >> 6;
                    bool act = tt < (lengths[b] - 1);
                    outF[((size_t)b * TM1 + tt) * VV + n] = act ? (val + bias[n]) : 0.f;
                }
            }
        }
    }
}

// f32 init GEMM on mean (h0|c0 partials) + reduce
__global__ __launch_bounds__(256)
void gemmInit(const float* __restrict__ Amat, const float* __restrict__ W1,
              const float* __restrict__ W2, float* __restrict__ C)
{
    __shared__ __align__(16) float As_[32][64];
    __shared__ __align__(16) float Ws_[32][64];
    const int tid = threadIdx.x;
    const int n0 = blockIdx.x * 64, kz = blockIdx.z, k0 = kz * 512;
    const int ty = tid >> 4, tx = tid & 15;
    float acc[4][4] = {};
    for (int kt = k0; kt < k0 + 512; kt += 32) {
        #pragma unroll
        for (int i = 0; i < 2; ++i) {
            int idx = tid + i * 256, row = idx >> 3, c4 = (idx & 7) * 4;
            float4 v = *reinterpret_cast<const float4*>(&Amat[(size_t)row * CENC + kt + c4]);
            As_[c4 + 0][row] = v.x; As_[c4 + 1][row] = v.y; As_[c4 + 2][row] = v.z; As_[c4 + 3][row] = v.w;
        }
        #pragma unroll
        for (int i = 0; i < 2; ++i) {
            int idx = tid + i * 256, row = idx >> 3, c4 = (idx & 7) * 4;
            int n = n0 + row;
            const float* wr = (n < 512) ? &W1[(size_t)n * CENC + kt + c4]
                                        : &W2[(size_t)(n - 512) * CENC + kt + c4];
            float4 v = *reinterpret_cast<const float4*>(wr);
            Ws_[c4 + 0][row] = v.x; Ws_[c4 + 1][row] = v.y; Ws_[c4 + 2][row] = v.z; Ws_[c4 + 3][row] = v.w;
        }
        __syncthreads();
        #pragma unroll
        for (int kk = 0; kk < 32; ++kk) {
            float av[4], bv[4];
            *reinterpret_cast<float4*>(av) = *reinterpret_cast<const float4*>(&As_[kk][ty * 4]);
            *reinterpret_cast<float4*>(bv) = *reinterpret_cast<const float4*>(&Ws_[kk][tx * 4]);
            #pragma unroll
            for (int ii = 0; ii < 4; ++ii)
                #pragma unroll
                for (int jj = 0; jj < 4; ++jj)
                    acc[ii][jj] = fmaf(av[ii], bv[jj], acc[ii][jj]);
        }
        __syncthreads();
    }
    #pragma unroll
    for (int ii = 0; ii < 4; ++ii)
        #pragma unroll
        for (int jj = 0; jj < 4; ++jj)
            C[((size_t)kz * 64 + ty * 4 + ii) * 1024 + n0 + tx * 4 + jj] = acc[ii][jj];
}

__global__ __launch_bounds__(256)
void kReduceHC(const float* __restrict__ Pc, const float* __restrict__ hb,
               const float* __restrict__ cb, float* __restrict__ hc,
               short* __restrict__ h16)
{
    int b = blockIdx.x, tid = threadIdx.x;
    for (int j = tid; j < 1024; j += 256) {
        float s = Pc[((size_t)0 * BB + b) * 1024 + j] + Pc[((size_t)1 * BB + b) * 1024 + j]
                + Pc[((size_t)2 * BB + b) * 1024 + j] + Pc[((size_t)3 * BB + b) * 1024 + j];
        s += (j < 512) ? hb[j] : cb[j - 512];
        hc[b * 1024 + j] = s;
        if (j < 512) h16[b * 512 + j] = f2bf(s);
    }
}

// ---------------------------------------------------------------------------
// Persistent decode loop: all 19 timesteps, 5 phases/step, grid barriers.
// grid = 256 blocks x 256 threads; LDS 16.5KB; VGPR <= 128 (2 blocks/CU safe).
// ---------------------------------------------------------------------------
template<int FULL>
__global__ __launch_bounds__(256, 2)
void kLoop(const float* __restrict__ encF, const short* __restrict__ enc16,
           const short* __restrict__ att1_16, const short* __restrict__ wcat16,
           const short* __restrict__ wihe16, const float* __restrict__ biascat,
           const float* __restrict__ gates_emb, const float* __restrict__ faw,
           const float* __restrict__ fab, const int* __restrict__ lengths,
           float* __restrict__ P3p, float* __restrict__ Pg,
           float* __restrict__ hc, short* __restrict__ h16,
           short* __restrict__ x16, float* __restrict__ alpha,
           short* __restrict__ allH, float* __restrict__ out_alpha,
           unsigned* __restrict__ bar)
{
    __shared__ __align__(16) char smem[16384];
    const int blk = blockIdx.x, tid = threadIdx.x;
    const int w = tid >> 6, l = tid & 63;
    const int l4 = l >> 4, l15 = l & 15;

    for (int t = 0; t < TM1; ++t) {
        // ---- P1: P3p[kz][64][4608] = h16 @ wcat16^T partials (144 blocks) ----
        if (blk < 144) {
            int nb = blk % 72, kz = blk / 72;
            int n0 = nb * 64, k0 = kz * 256;
            short* As = (short*)smem;
            short* Ws = (short*)(smem + 8192);
            floatx4 acc[4] = {};
            for (int ks = 0; ks < 4; ++ks) {
                int kt = k0 + ks * 64;
                #pragma unroll
                for (int i = 0; i < 2; ++i) {
                    int s = tid + i * 256, row = s >> 3, cg = s & 7;
                    int4v v = *reinterpret_cast<const int4v*>(&h16[row * 512 + kt + cg * 8]);
                    *reinterpret_cast<int4v*>(&As[row * 64 + ((cg ^ (row & 7)) << 3)]) = v;
                }
                #pragma unroll
                for (int i = 0; i < 2; ++i) {
                    int s = tid + i * 256, r = s >> 3, cg = s & 7;
                    int4v v = *reinterpret_cast<const int4v*>(&wcat16[(size_t)(n0 + r) * 512 + kt + cg * 8]);
                    *reinterpret_cast<int4v*>(&Ws[r * 64 + ((cg ^ (r & 7)) << 3)]) = v;
                }
                __syncthreads();
                #pragma unroll
                for (int kc = 0; kc < 2; ++kc) {
                    int arow = 16 * w + l15;
                    int cg = 4 * kc + l4;
                    short8 af = *reinterpret_cast<const short8*>(&As[arow * 64 + ((cg ^ (arow & 7)) << 3)]);
                    #pragma unroll
                    for (int q = 0; q < 4; ++q) {
                        int wrow = 16 * q + l15;
                        short8 wf = *reinterpret_cast<const short8*>(&Ws[wrow * 64 + ((cg ^ (wrow & 7)) << 3)]);
                        acc[q] = __builtin_amdgcn_mfma_f32_16x16x32_bf16(af, wf, acc[q], 0, 0, 0);
                    }
                }
                __syncthreads();
            }
            #pragma unroll
            for (int q = 0; q < 4; ++q)
                #pragma unroll
                for (int j = 0; j < 4; ++j) {
                    int m = 16 * w + 4 * l4 + j;
                    int n = n0 + 16 * q + l15;
                    P3p[(size_t)kz * 294912 + m * 4608 + n] = acc[q][j];
                }
        }
        gridBarrier(bar);

        // ---- P2: e/softmax/alpha (64 blocks) ----
        if (blk < 64) {
            int b = blk;
            float* att2s = (float*)smem;
            float* fw    = (float*)(smem + 2048);
            float* es    = (float*)(smem + 4096);
            float* red   = (float*)(smem + 4896);
            for (int a = tid; a < 512; a += 256) {
                att2s[a] = P3p[b * 4608 + a] + P3p[294912 + b * 4608 + a] + biascat[a];
                fw[a] = faw[a];
            }
            __syncthreads();
            for (int p = w; p < PP; p += 4) {
                short8 v = *reinterpret_cast<const short8*>(&att1_16[((size_t)b * PP + p) * 512 + l * 8]);
                float s = 0.f;
                #pragma unroll
                for (int j = 0; j < 8; ++j) {
                    float x = bf2f(v[j]) + att2s[l * 8 + j];
                    s += fmaxf(x, 0.f) * fw[l * 8 + j];
                }
                #pragma unroll
                for (int off = 32; off > 0; off >>= 1) s += __shfl_down(s, off, 64);
                if (l == 0) es[p] = s + fab[0];
            }
            __syncthreads();
            float m_ = -1e30f;
            for (int p = tid; p < PP; p += 256) m_ = fmaxf(m_, es[p]);
            #pragma unroll
            for (int off = 32; off > 0; off >>= 1) m_ = fmaxf(m_, __shfl_down(m_, off, 64));
            if (l == 0) red[w] = m_;
            __syncthreads();
            m_ = fmaxf(fmaxf(red[0], red[1]), fmaxf(red[2], red[3]));
            float ssum = 0.f;
            for (int p = tid; p < PP; p += 256) { float ev = expf(es[p] - m_); es[p] = ev; ssum += ev; }
            #pragma unroll
            for (int off = 32; off > 0; off >>= 1) ssum += __shfl_down(ssum, off, 64);
            if (l == 0) red[4 + w] = ssum;
            __syncthreads();
            float inv = 1.f / (red[4] + red[5] + red[6] + red[7]);
            bool active = t < (lengths[b] - 1);
            for (int p = tid; p < PP; p += 256) {
                float al = es[p] * inv;
                alpha[b * PP + p] = al;
                out_alpha[((size_t)b * TM1 + t) * PP + p] = active ? al : 0.f;
            }
        }
        gridBarrier(bar);

        // ---- P3: awe + gate -> x16 (256 blocks: b = blk>>2, 512-col slice) ----
        {
            int b = blk >> 2, kc = blk & 3;
            float* al   = (float*)smem;
            float* part = (float*)(smem + 1024);
            for (int p = tid; p < PP; p += 256) al[p] = alpha[b * PP + p];
            __syncthreads();
            if (FULL) {
                int g = tid & 63, prow = tid >> 6;
                const short* eb = &enc16[(size_t)b * PP * CENC + kc * 512 + g * 8];
                float acc8[8] = {};
                for (int p = prow; p < PP; p += 4) {
                    short8 v = *reinterpret_cast<const short8*>(&eb[(size_t)p * CENC]);
                    float a_ = al[p];
                    #pragma unroll
                    for (int j = 0; j < 8; ++j) acc8[j] = fmaf(bf2f(v[j]), a_, acc8[j]);
                }
                #pragma unroll
                for (int j = 0; j < 8; ++j) part[prow * 512 + g * 8 + j] = acc8[j];
                __syncthreads();
                #pragma unroll
                for (int ci = 0; ci < 2; ++ci) {
                    int c = tid + ci * 256;
                    float awe = part[c] + part[512 + c] + part[1024 + c] + part[1536 + c];
                    int n = kc * 512 + c;
                    float graw = P3p[b * 4608 + 512 + n] + P3p[294912 + b * 4608 + 512 + n] + biascat[512 + n];
                    float gate = 1.f / (1.f + expf(-graw));
                    x16[b * 2048 + n] = f2bf(gate * awe);
                }
            } else {
                int g = tid & 127, prow = tid >> 7;
                const float* eb = &encF[(size_t)b * PP * CENC + kc * 512 + g * 4];
                float acc4[4] = {};
                for (int p = prow; p < PP; p += 2) {
                    float4 v = *reinterpret_cast<const float4*>(&eb[(size_t)p * CENC]);
                    float a_ = al[p];
                    acc4[0] = fmaf(v.x, a_, acc4[0]); acc4[1] = fmaf(v.y, a_, acc4[1]);
                    acc4[2] = fmaf(v.z, a_, acc4[2]); acc4[3] = fmaf(v.w, a_, acc4[3]);
                }
                #pragma unroll
                for (int j = 0; j < 4; ++j) part[prow * 512 + g * 4 + j] = acc4[j];
                __syncthreads();
                #pragma unroll
                for (int ci = 0; ci < 2; ++ci) {
                    int c = tid + ci * 256;
                    float awe = part[c] + part[512 + c];
                    int n = kc * 512 + c;
                    float graw = P3p[b * 4608 + 512 + n] + P3p[294912 + b * 4608 + 512 + n] + biascat[512 + n];
                    float gate = 1.f / (1.f + expf(-graw));
                    x16[b * 2048 + n] = f2bf(gate * awe);
                }
            }
        }
        gridBarrier(bar);

        // ---- P4: gate partials Pg[kz][64][2048] = x16 @ wihe16^T (256 blocks) ----
        {
            int nb = blk & 31, kz = blk >> 5;
            int k0 = kz * 256;
            short* As = (short*)smem;
            short* Ws = (short*)(smem + 8192);
            floatx4 acc[4] = {};
            for (int ks = 0; ks < 4; ++ks) {
                int kt = k0 + ks * 64;
                #pragma unroll
                for (int i = 0; i < 2; ++i) {
                    int s = tid + i * 256, row = s >> 3, cg = s & 7;
                    int4v v = *reinterpret_cast<const int4v*>(&x16[row * 2048 + kt + cg * 8]);
                    *reinterpret_cast<int4v*>(&As[row * 64 + ((cg ^ (row & 7)) << 3)]) = v;
                }
                #pragma unroll
                for (int i = 0; i < 2; ++i) {
                    int s = tid + i * 256, r = s >> 3, cg = s & 7;
                    int wr = 512 * (r >> 4) + 16 * nb + (r & 15);   // gate-interleaved
                    int4v v = *reinterpret_cast<const int4v*>(&wihe16[(size_t)wr * 2048 + kt + cg * 8]);
                    *reinterpret_cast<int4v*>(&Ws[r * 64 + ((cg ^ (r & 7)) << 3)]) = v;
                }
                __syncthreads();
                #pragma unroll
                for (int kc = 0; kc < 2; ++kc) {
                    int arow = 16 * w + l15;
                    int cg = 4 * kc + l4;
                    short8 af = *reinterpret_cast<const short8*>(&As[arow * 64 + ((cg ^ (arow & 7)) << 3)]);
                    #pragma unroll
                    for (int q = 0; q < 4; ++q) {
                        int wrow = 16 * q + l15;
                        short8 wf = *reinterpret_cast<const short8*>(&Ws[wrow * 64 + ((cg ^ (wrow & 7)) << 3)]);
                        acc[q] = __builtin_amdgcn_mfma_f32_16x16x32_bf16(af, wf, acc[q], 0, 0, 0);
                    }
                }
                __syncthreads();
            }
            #pragma unroll
            for (int q = 0; q < 4; ++q)
                #pragma unroll
                for (int j = 0; j < 4; ++j) {
                    int m = 16 * w + 4 * l4 + j;
                    int col = 512 * q + 16 * nb + l15;
                    Pg[(size_t)kz * 131072 + m * 2048 + col] = acc[q][j];
                }
        }
        gridBarrier(bar);

        // ---- P5: LSTM cell update (64 blocks) ----
        if (blk < 64) {
            int b = blk;
            for (int d = tid; d < 512; d += 256) {
                float g4[4];
                #pragma unroll
                for (int q = 0; q < 4; ++q) {
                    int col = 512 * q + d;
                    float s = gates_emb[((size_t)t * 64 + b) * 2048 + col]
                            + P3p[b * 4608 + 2560 + col] + P3p[294912 + b * 4608 + 2560 + col];
                    #pragma unroll
                    for (int kz = 0; kz < 8; ++kz) s += Pg[(size_t)kz * 131072 + b * 2048 + col];
                    g4[q] = s;
                }
                float i_ = 1.f / (1.f + expf(-g4[0]));
                float f_ = 1.f / (1.f + expf(-g4[1]));
                float g_ = tanhf(g4[2]);
                float o_ = 1.f / (1.f + expf(-g4[3]));
                float c_new = f_ * hc[b * 1024 + 512 + d] + i_ * g_;
                float h_new = o_ * tanhf(c_new);
                hc[b * 1024 + 512 + d] = c_new;
                h16[b * 512 + d] = f2bf(h_new);
                allH[((size_t)t * 64 + b) * 512 + d] = f2bf(h_new);
            }
        }
        gridBarrier(bar);
    }
}

extern "C" void kernel_launch(void* const* d_in, const int* in_sizes, int n_in,
                              void* d_out, int out_size, void* d_ws, size_t ws_size,
                              hipStream_t stream)
{
    const float* enc        = (const float*)d_in[0];
    const int*   captions   = (const int*)d_in[1];
    const int*   lengths    = (const int*)d_in[2];
    const float* enc_att_w  = (const float*)d_in[3];
    const float* enc_att_b  = (const float*)d_in[4];
    const float* hid_att_w  = (const float*)d_in[5];
    const float* hid_att_b  = (const float*)d_in[6];
    const float* fbeta_w    = (const float*)d_in[18];
    const float* fbeta_b    = (const float*)d_in[19];
    const float* full_att_w = (const float*)d_in[7];
    const float* full_att_b = (const float*)d_in[8];
    const float* embw       = (const float*)d_in[9];
    const float* w_ih       = (const float*)d_in[10];
    const float* w_hh       = (const float*)d_in[11];
    const float* b_ih       = (const float*)d_in[12];
    const float* b_hh       = (const float*)d_in[13];
    const float* init_h_w   = (const float*)d_in[14];
    const float* init_h_b   = (const float*)d_in[15];
    const float* init_c_w   = (const float*)d_in[16];
    const float* init_c_b   = (const float*)d_in[17];
    const float* fc_w       = (const float*)d_in[20];
    const float* fc_b       = (const float*)d_in[21];

    float* out_pred  = (float*)d_out;                        // [64][19][10000]
    float* out_alpha = out_pred + (size_t)BB * TM1 * VV;     // [64][19][196]

    // ---- scratch in d_out pred region; loop-live first, then precompute-dead
    char* pr = (char*)d_out;
    short* att1_16   = (short*)pr;  pr += 12845056;  // live in loop
    float* gates_emb = (float*)pr;  pr += 9961472;   // live
    short* wcat16    = (short*)pr;  pr += 4718592;   // live
    short* wihe16    = (short*)pr;  pr += 8388608;   // live
    float* biascat   = (float*)pr;  pr += 18432;     // live
    float* P3p       = (float*)pr;  pr += 2359296;   // live
    float* Pg        = (float*)pr;  pr += 4194304;   // live  (sum 42.49 MB)
    short* encw16    = (short*)pr;  pr += 2097152;   // dead before loop
    short* wihm16    = (short*)pr;  pr += 2097152;   // dead
    short* embA      = (short*)pr;  pr += 1245184;   // dead
    float* biasg     = (float*)pr;  pr += 8192;      // dead
    float* mean      = (float*)pr;  pr += 524288;    // dead
    float* hcP       = (float*)pr;  pr += 1048576;   // dead (spills into out_alpha region; ok)

    // ---- workspace
    char* wp = (char*)d_ws;
    unsigned* bar = (unsigned*)wp;  wp += 256;
    float* hc    = (float*)wp;  wp += 262144;
    short* h16   = (short*)wp;  wp += 65536;
    short* x16   = (short*)wp;  wp += 262144;
    float* alpha = (float*)wp;  wp += 50176;
    short* fc16  = (short*)wp;  wp += 10240000;
    short* allH  = (short*)wp;  wp += 1245184;
    short* enc16 = (short*)wp;  wp += 51380224;      // optional
    const bool full = ((size_t)(wp - (char*)d_ws) <= ws_size);

    hipMemsetAsync(bar, 0, 256, stream);

    // ---- precompute ----
    kPrepW<<<6728, 256, 0, stream>>>(enc_att_w, hid_att_w, fbeta_w, w_hh, w_ih, fc_w,
                                     hid_att_b, fbeta_b, b_ih, b_hh,
                                     encw16, wcat16, wihe16, wihm16, fc16, biascat, biasg);
    if (full) kMeanEnc<1><<<dim3(64, 8), 256, 0, stream>>>(enc, enc16, mean);
    else      kMeanEnc<0><<<dim3(64, 8), 256, 0, stream>>>(enc, enc16, mean);
    kEmbGather<<<304, 256, 0, stream>>>(embw, captions, embA);
    gemmInit<<<dim3(16, 1, 4), 256, 0, stream>>>(mean, init_h_w, init_c_w, hcP);
    kReduceHC<<<64, 256, 0, stream>>>(hcP, init_h_b, init_c_b, hc, h16);

    // att1 = enc @ enc_att_w^T + b -> bf16 [12544][512]
    if (full)
        kGemm<0, 1, 1><<<1568, 256, 0, stream>>>(enc16, CENC, encw16, CENC,
            enc_att_b, 512, nullptr, 512, att1_16, 32, nullptr);
    else
        kGemm<1, 1, 1><<<1568, 256, 0, stream>>>(enc, CENC, encw16, CENC,
            enc_att_b, 512, nullptr, 512, att1_16, 32, nullptr);

    // gates_emb = embA @ W_ih[:, :512]^T + (b_ih + b_hh)  -> f32 [1216][2048]
    kGemm<0, 0, 0><<<dim3(32, 19, 1), 256, 0, stream>>>(embA, 512, wihm16, 512,
        biasg, 2048, gates_emb, 2048, nullptr, 8, nullptr);

    // ---- the whole 19-step decode in ONE persistent kernel ----
    if (full)
        kLoop<1><<<NBLK, 256, 0, stream>>>(enc, enc16, att1_16, wcat16, wihe16,
            biascat, gates_emb, full_att_w, full_att_b, lengths,
            P3p, Pg, hc, h16, x16, alpha, allH, out_alpha, bar);
    else
        kLoop<0><<<NBLK, 256, 0, stream>>>(enc, enc16, att1_16, wcat16, wihe16,
            biascat, gates_emb, full_att_w, full_att_b, lengths,
            P3p, Pg, hc, h16, x16, alpha, allH, out_alpha, bar);

    // ---- pred = allH @ fc_w^T + fc_b (masked, remapped) ----
    kGemm<0, 2, 2><<<3040, 256, 0, stream>>>(allH, 512, fc16, 512,
        fc_b, VV, out_pred, VV, nullptr, 8, lengths);
}

// Round 4
// 2449.104 us; speedup vs baseline: 2.9478x; 2.9478x over previous
//
#include <hip/hip_runtime.h>
#include <hip/hip_bf16.h>

typedef short short8  __attribute__((ext_vector_type(8)));
typedef short short4v __attribute__((ext_vector_type(4)));
typedef float floatx4 __attribute__((ext_vector_type(4)));
typedef int   int4v   __attribute__((ext_vector_type(4)));

constexpr int BB = 64, PP = 196, CENC = 2048, HH = 512, AA = 512, EE = 512;
constexpr int VV = 10000, TT = 20, TM1 = 19;

__device__ __forceinline__ float bf2f(short u) {
    union { unsigned u; float f; } v; v.u = ((unsigned)(unsigned short)u) << 16; return v.f;
}
__device__ __forceinline__ short f2bf(float f) {
    union { float f; unsigned u; } v; v.f = f;
    unsigned r = v.u + 0x7FFF + ((v.u >> 16) & 1);
    return (short)(r >> 16);
}
__device__ __forceinline__ float fsigmoid(float x) {
    return 1.f / (1.f + __expf(-x));
}

// ---------------------------------------------------------------------------
// Weight prep: f32 -> bf16 conversions + concatenations + transposes + biases.
// Linear element space, 8 elems (16B bf16) per thread. 6725 blocks x 256.
// Segments:
//  [0,        1048576): encw16   <- enc_att_w [512][2048]
//  [1048576,  3145728): projW16  <- [fbeta_w(2048) ; w_hh(2048)] x 512
//  [3145728,  8388608): wih16    <- w_ih flat [2048][2560]
//  [8388608, 13508608): fc16     <- fc_w flat [10000][512]
//  [13508608,13770752): hidattT  <- hid_att_w^T  [512 k][512 a]
//  [13770752,13772800): biasg    <- b_ih + b_hh (f32)
// ---------------------------------------------------------------------------
__global__ __launch_bounds__(256)
void kPrepW(const float* __restrict__ encw_s, const float* __restrict__ haw,
            const float* __restrict__ fbw, const float* __restrict__ whh,
            const float* __restrict__ wih, const float* __restrict__ fcw,
            const float* __restrict__ bih, const float* __restrict__ bhh,
            short* __restrict__ encw16, short* __restrict__ projW16,
            short* __restrict__ wih16, short* __restrict__ fc16,
            short* __restrict__ hidattT, float* __restrict__ biasg)
{
    long e = ((long)blockIdx.x * 256 + threadIdx.x) * 8;
    union { short s[8]; int4v v; } u8;
    if (e < 1048576) {
        #pragma unroll
        for (int j = 0; j < 8; ++j) u8.s[j] = f2bf(encw_s[e + j]);
        *reinterpret_cast<int4v*>(&encw16[e]) = u8.v;
    } else if (e < 3145728) {
        long u = e - 1048576; long row = u >> 9, col = u & 511;
        const float* sp = (row < 2048) ? &fbw[row * 512 + col] : &whh[(row - 2048) * 512 + col];
        #pragma unroll
        for (int j = 0; j < 8; ++j) u8.s[j] = f2bf(sp[j]);
        *reinterpret_cast<int4v*>(&projW16[u]) = u8.v;
    } else if (e < 8388608) {
        long u = e - 3145728;
        #pragma unroll
        for (int j = 0; j < 8; ++j) u8.s[j] = f2bf(wih[u + j]);
        *reinterpret_cast<int4v*>(&wih16[u]) = u8.v;
    } else if (e < 13508608) {
        long u = e - 8388608;
        #pragma unroll
        for (int j = 0; j < 8; ++j) u8.s[j] = f2bf(fcw[u + j]);
        *reinterpret_cast<int4v*>(&fc16[u]) = u8.v;
    } else if (e < 13770752) {
        long u = e - 13508608; long k = u >> 9, a0 = u & 511;
        #pragma unroll
        for (int j = 0; j < 8; ++j) u8.s[j] = f2bf(haw[(a0 + j) * 512 + k]);
        *reinterpret_cast<int4v*>(&hidattT[u]) = u8.v;
    } else if (e < 13772800) {
        long u = e - 13770752;
        #pragma unroll
        for (int j = 0; j < 8; ++j) biasg[u + j] = bih[u + j] + bhh[u + j];
    }
}

// Fused: mean over P + enc f32->bf16 (single pass). grid (64,8) x 256.
template<int FULL>
__global__ __launch_bounds__(256)
void kMeanEnc(const float* __restrict__ enc, short* __restrict__ enc16,
              float* __restrict__ mean)
{
    int b = blockIdx.x;
    int k = blockIdx.y * 256 + threadIdx.x;
    const float* eb = &enc[(size_t)b * PP * CENC + k];
    short* ob = &enc16[(size_t)b * PP * CENC + k];
    float s0 = 0, s1 = 0, s2 = 0, s3 = 0;
    for (int p = 0; p < PP; p += 4) {
        float v0 = eb[(size_t)(p + 0) * CENC], v1 = eb[(size_t)(p + 1) * CENC];
        float v2 = eb[(size_t)(p + 2) * CENC], v3 = eb[(size_t)(p + 3) * CENC];
        s0 += v0; s1 += v1; s2 += v2; s3 += v3;
        if (FULL) {
            ob[(size_t)(p + 0) * CENC] = f2bf(v0); ob[(size_t)(p + 1) * CENC] = f2bf(v1);
            ob[(size_t)(p + 2) * CENC] = f2bf(v2); ob[(size_t)(p + 3) * CENC] = f2bf(v3);
        }
    }
    mean[b * CENC + k] = ((s0 + s1) + (s2 + s3)) * (1.0f / PP);
}

// embedding gather -> embA[r = t*64+b][512] bf16
__global__ __launch_bounds__(256)
void kEmbGather(const float* __restrict__ embw, const int* __restrict__ captions,
                short* __restrict__ embA)
{
    long e = ((long)blockIdx.x * 256 + threadIdx.x) * 8;
    int r = (int)(e >> 9), j = (int)(e & 511);
    int t = r >> 6, b = r & 63;
    int tok = captions[b * TT + t];
    const float* sp = &embw[(size_t)tok * EE + j];
    union { short s[8]; int4v v; } u8;
    #pragma unroll
    for (int q = 0; q < 8; ++q) u8.s[q] = f2bf(sp[q]);
    *reinterpret_cast<int4v*>(&embA[e]) = u8.v;
}

// ---------------------------------------------------------------------------
// MFMA bf16 GEMM for att1 + pred: C[M,N] = A[M,K] @ W[N,K]^T.
// AOP: 0 = A bf16; 1 = A f32 (convert during staging)
// EOP: 1 = bf16 out +bias; 2 = pred f32 (mask/remap)
// SWZ: 1 = att1 XCD-group swizzle (1568 blk); 2 = pred swizzle (3040 blk)
// ---------------------------------------------------------------------------
template<int AOP, int EOP, int SWZ>
__global__ __launch_bounds__(256)
void kGemm(const void* __restrict__ Ap, int lda, const short* __restrict__ W, int ldw,
           const float* __restrict__ bias, int Ntot,
           float* __restrict__ outF, int ldc, short* __restrict__ outB,
           int nk, const int* __restrict__ lengths)
{
    __shared__ short As[64 * 64];
    __shared__ short Ws[64 * 64];
    int nb, mb;
    if (SWZ == 1) {
        int j = blockIdx.x;
        if (j < 1536) { mb = (j >> 6) * 8 + (j & 7); nb = (j >> 3) & 7; }
        else          { int u = j - 1536; mb = 192 + (u >> 3); nb = u & 7; }
    } else {
        int j = blockIdx.x; int c = j & 7, s = j >> 3;
        mb = s % 19; int u = s / 19; nb = 8 * u + c;
        if (nb * 64 >= Ntot) return;
    }
    const int tid = threadIdx.x;
    const int m0 = mb * 64, n0 = nb * 64;
    const int w = tid >> 6, l = tid & 63;
    floatx4 acc[4] = {};

    for (int ks = 0; ks < nk; ++ks) {
        int kt = ks * 64;
        if (AOP == 0) {
            const short* A = (const short*)Ap;
            #pragma unroll
            for (int i = 0; i < 2; ++i) {
                int s = tid + i * 256, row = s >> 3, cg = s & 7;
                int4v v = *reinterpret_cast<const int4v*>(&A[(size_t)(m0 + row) * lda + kt + cg * 8]);
                *reinterpret_cast<int4v*>(&As[row * 64 + ((cg ^ (row & 7)) << 3)]) = v;
            }
        } else {
            const float* A = (const float*)Ap;
            #pragma unroll
            for (int i = 0; i < 2; ++i) {
                int s = tid + i * 256, row = s >> 3, cg = s & 7;
                const float* sp = &A[(size_t)(m0 + row) * lda + kt + cg * 8];
                float4 a = *reinterpret_cast<const float4*>(sp);
                float4 b = *reinterpret_cast<const float4*>(sp + 4);
                union { short s[8]; int4v v; } u8;
                u8.s[0]=f2bf(a.x); u8.s[1]=f2bf(a.y); u8.s[2]=f2bf(a.z); u8.s[3]=f2bf(a.w);
                u8.s[4]=f2bf(b.x); u8.s[5]=f2bf(b.y); u8.s[6]=f2bf(b.z); u8.s[7]=f2bf(b.w);
                *reinterpret_cast<int4v*>(&As[row * 64 + ((cg ^ (row & 7)) << 3)]) = u8.v;
            }
        }
        #pragma unroll
        for (int i = 0; i < 2; ++i) {
            int s = tid + i * 256, r = s >> 3, cg = s & 7;
            int4v v = {0, 0, 0, 0};
            int wr = n0 + r;
            if (wr < Ntot)
                v = *reinterpret_cast<const int4v*>(&W[(size_t)wr * ldw + kt + cg * 8]);
            *reinterpret_cast<int4v*>(&Ws[r * 64 + ((cg ^ (r & 7)) << 3)]) = v;
        }
        __syncthreads();
        #pragma unroll
        for (int kc = 0; kc < 2; ++kc) {
            int arow = 16 * w + (l & 15);
            int cg = 4 * kc + (l >> 4);
            short8 af = *reinterpret_cast<const short8*>(&As[arow * 64 + ((cg ^ (arow & 7)) << 3)]);
            #pragma unroll
            for (int q = 0; q < 4; ++q) {
                int wrow = 16 * q + (l & 15);
                short8 wf = *reinterpret_cast<const short8*>(&Ws[wrow * 64 + ((cg ^ (wrow & 7)) << 3)]);
                acc[q] = __builtin_amdgcn_mfma_f32_16x16x32_bf16(af, wf, acc[q], 0, 0, 0);
            }
        }
        __syncthreads();
    }
    int l4 = l >> 4, l15 = l & 15;
    #pragma unroll
    for (int q = 0; q < 4; ++q) {
        #pragma unroll
        for (int j = 0; j < 4; ++j) {
            int m = m0 + 16 * w + 4 * l4 + j;
            int n = n0 + 16 * q + l15;
            float val = acc[q][j];
            if (EOP == 1) {
                outB[(size_t)m * ldc + n] = f2bf(val + bias[n]);
            } else {
                if (n < Ntot) {
                    int b = m & 63, tt = m >> 6;
                    bool act = tt < (lengths[b] - 1);
                    outF[((size_t)b * TM1 + tt) * VV + n] = act ? (val + bias[n]) : 0.f;
                }
            }
        }
    }
}

// f32 init GEMM on mean (h0|c0 partials, k-split x4) + reduce
__global__ __launch_bounds__(256)
void gemmInit(const float* __restrict__ Amat, const float* __restrict__ W1,
              const float* __restrict__ W2, float* __restrict__ C)
{
    __shared__ __align__(16) float As_[32][64];
    __shared__ __align__(16) float Ws_[32][64];
    const int tid = threadIdx.x;
    const int n0 = blockIdx.x * 64, kz = blockIdx.z, k0 = kz * 512;
    const int ty = tid >> 4, tx = tid & 15;
    float acc[4][4] = {};
    for (int kt = k0; kt < k0 + 512; kt += 32) {
        #pragma unroll
        for (int i = 0; i < 2; ++i) {
            int idx = tid + i * 256, row = idx >> 3, c4 = (idx & 7) * 4;
            float4 v = *reinterpret_cast<const float4*>(&Amat[(size_t)row * CENC + kt + c4]);
            As_[c4 + 0][row] = v.x; As_[c4 + 1][row] = v.y; As_[c4 + 2][row] = v.z; As_[c4 + 3][row] = v.w;
        }
        #pragma unroll
        for (int i = 0; i < 2; ++i) {
            int idx = tid + i * 256, row = idx >> 3, c4 = (idx & 7) * 4;
            int n = n0 + row;
            const float* wr = (n < 512) ? &W1[(size_t)n * CENC + kt + c4]
                                        : &W2[(size_t)(n - 512) * CENC + kt + c4];
            float4 v = *reinterpret_cast<const float4*>(wr);
            Ws_[c4 + 0][row] = v.x; Ws_[c4 + 1][row] = v.y; Ws_[c4 + 2][row] = v.z; Ws_[c4 + 3][row] = v.w;
        }
        __syncthreads();
        #pragma unroll
        for (int kk = 0; kk < 32; ++kk) {
            float av[4], bv[4];
            *reinterpret_cast<float4*>(av) = *reinterpret_cast<const float4*>(&As_[kk][ty * 4]);
            *reinterpret_cast<float4*>(bv) = *reinterpret_cast<const float4*>(&Ws_[kk][tx * 4]);
            #pragma unroll
            for (int ii = 0; ii < 4; ++ii)
                #pragma unroll
                for (int jj = 0; jj < 4; ++jj)
                    acc[ii][jj] = fmaf(av[ii], bv[jj], acc[ii][jj]);
        }
        __syncthreads();
    }
    #pragma unroll
    for (int ii = 0; ii < 4; ++ii)
        #pragma unroll
        for (int jj = 0; jj < 4; ++jj)
            C[((size_t)kz * 64 + ty * 4 + ii) * 1024 + n0 + tx * 4 + jj] = acc[ii][jj];
}

__global__ __launch_bounds__(256)
void kReduceHC(const float* __restrict__ Pc, const float* __restrict__ hb,
               const float* __restrict__ cb, float* __restrict__ hc,
               short* __restrict__ h16)
{
    int b = blockIdx.x, tid = threadIdx.x;
    for (int j = tid; j < 1024; j += 256) {
        float s = Pc[((size_t)0 * BB + b) * 1024 + j] + Pc[((size_t)1 * BB + b) * 1024 + j]
                + Pc[((size_t)2 * BB + b) * 1024 + j] + Pc[((size_t)3 * BB + b) * 1024 + j];
        s += (j < 512) ? hb[j] : cb[j - 512];
        hc[b * 1024 + j] = s;
        if (j < 512) h16[b * 512 + j] = f2bf(s);
    }
}

// ---------------------------------------------------------------------------
// Step kernel A (96 blocks x 512 threads):
//   blocks 0..63  (per-b): att2 = h@hidattT (+b), e = relu(att1+att2)@faw+fab,
//                 softmax -> alpha (LDS only, masked copy to out_alpha),
//                 awe = alpha @ enc_b -> awe16 (raw, ungated)
//   blocks 64..95 (GEMM): projP[64][4096] = h @ [fbeta;whh]^T (+fbeta_b on n<2048)
// ---------------------------------------------------------------------------
template<int FULL>
__global__ __launch_bounds__(512)
void kStepA(const short* __restrict__ h16, const short* __restrict__ hidattT,
            const float* __restrict__ hid_att_b, const short* __restrict__ att1_16,
            const float* __restrict__ faw, const float* __restrict__ fab,
            const int* __restrict__ lengths, const short* __restrict__ projW,
            const float* __restrict__ fbb, const void* __restrict__ encp,
            float* __restrict__ projP, short* __restrict__ awe16,
            float* __restrict__ out_alpha, int t)
{
    __shared__ __align__(16) char smem[24576];
    const int blk = blockIdx.x, tid = threadIdx.x;
    const int w = tid >> 6, l = tid & 63;

    if (blk < 64) {
        const int b = blk;
        float* hsh   = (float*)smem;            // 512 f
        float* fwsh  = (float*)(smem + 2048);   // 512 f
        float* att2s = (float*)(smem + 4096);   // 512 f
        float* es    = (float*)(smem + 6144);   // 200 f
        float* alps  = (float*)(smem + 6944);   // 200 f
        float* red   = (float*)(smem + 7744);   // 16 f

        hsh[tid]  = bf2f(h16[b * 512 + tid]);
        fwsh[tid] = faw[tid];
        __syncthreads();

        // att2[a] = hid_att_b[a] + sum_k h[k] * hidattT[k][a]   (coalesced over a)
        {
            float s = hid_att_b[tid];
            for (int k = 0; k < 512; k += 8) {
                #pragma unroll
                for (int j = 0; j < 8; ++j)
                    s = fmaf(bf2f(hidattT[(k + j) * 512 + tid]), hsh[k + j], s);
            }
            att2s[tid] = s;
        }
        __syncthreads();

        // e[p] = relu(att1[p]+att2) . faw + fab   (one p per wave)
        for (int p = w; p < PP; p += 8) {
            short8 v = *reinterpret_cast<const short8*>(&att1_16[((size_t)b * PP + p) * 512 + l * 8]);
            float s = 0.f;
            #pragma unroll
            for (int j = 0; j < 8; ++j) {
                float x = bf2f(v[j]) + att2s[l * 8 + j];
                s += fmaxf(x, 0.f) * fwsh[l * 8 + j];
            }
            #pragma unroll
            for (int off = 32; off > 0; off >>= 1) s += __shfl_down(s, off, 64);
            if (l == 0) es[p] = s + fab[0];
        }
        __syncthreads();

        // softmax over 196
        float m_ = (tid < PP) ? es[tid] : -1e30f;
        #pragma unroll
        for (int off = 32; off > 0; off >>= 1) m_ = fmaxf(m_, __shfl_down(m_, off, 64));
        if (l == 0) red[w] = m_;
        __syncthreads();
        float mm = red[0];
        #pragma unroll
        for (int i = 1; i < 8; ++i) mm = fmaxf(mm, red[i]);
        float ev = 0.f;
        if (tid < PP) { ev = __expf(es[tid] - mm); alps[tid] = ev; }
        #pragma unroll
        for (int off = 32; off > 0; off >>= 1) ev += __shfl_down(ev, off, 64);
        if (l == 0) red[8 + w] = ev;
        __syncthreads();
        float ssum = red[8];
        #pragma unroll
        for (int i = 1; i < 8; ++i) ssum += red[8 + i];
        float inv = 1.f / ssum;
        bool active = t < (lengths[b] - 1);
        if (tid < PP) {
            float al = alps[tid] * inv;
            alps[tid] = al;
            out_alpha[((size_t)b * TM1 + t) * PP + tid] = active ? al : 0.f;
        }
        __syncthreads();

        // awe[c0..c0+3] = sum_p alpha[p] * enc[b][p][c]
        int c0 = tid * 4;
        float a0 = 0, a1 = 0, a2 = 0, a3 = 0;
        if (FULL) {
            const short* eb = &((const short*)encp)[(size_t)b * PP * CENC + c0];
            for (int p = 0; p < PP; ++p) {
                short4v v = *reinterpret_cast<const short4v*>(&eb[(size_t)p * CENC]);
                float al = alps[p];
                a0 = fmaf(bf2f(v[0]), al, a0); a1 = fmaf(bf2f(v[1]), al, a1);
                a2 = fmaf(bf2f(v[2]), al, a2); a3 = fmaf(bf2f(v[3]), al, a3);
            }
        } else {
            const float* eb = &((const float*)encp)[(size_t)b * PP * CENC + c0];
            for (int p = 0; p < PP; ++p) {
                float4 v = *reinterpret_cast<const float4*>(&eb[(size_t)p * CENC]);
                float al = alps[p];
                a0 = fmaf(v.x, al, a0); a1 = fmaf(v.y, al, a1);
                a2 = fmaf(v.z, al, a2); a3 = fmaf(v.w, al, a3);
            }
        }
        short4v o; o[0] = f2bf(a0); o[1] = f2bf(a1); o[2] = f2bf(a2); o[3] = f2bf(a3);
        *reinterpret_cast<short4v*>(&awe16[b * CENC + c0]) = o;
    } else {
        // ---- proj GEMM: M=64, N=128/block, K=512 full ----
        const int nb = blk - 64;
        const int n0 = nb * 128;
        short* As = (short*)smem;            // 64x64 bf16 = 8KB
        short* Ws = (short*)(smem + 8192);   // 128x64 bf16 = 16KB
        const int wq = w & 3, half = w >> 2;
        const int l4 = l >> 4, l15 = l & 15;
        floatx4 acc[4] = {};
        for (int ks = 0; ks < 8; ++ks) {
            int kt = ks * 64;
            {
                int s = tid, row = s >> 3, cg = s & 7;
                int4v v = *reinterpret_cast<const int4v*>(&h16[row * 512 + kt + cg * 8]);
                *reinterpret_cast<int4v*>(&As[row * 64 + ((cg ^ (row & 7)) << 3)]) = v;
            }
            #pragma unroll
            for (int i = 0; i < 2; ++i) {
                int s = tid + i * 512, r = s >> 3, cg = s & 7;
                int4v v = *reinterpret_cast<const int4v*>(&projW[(size_t)(n0 + r) * 512 + kt + cg * 8]);
                *reinterpret_cast<int4v*>(&Ws[r * 64 + ((cg ^ (r & 7)) << 3)]) = v;
            }
            __syncthreads();
            #pragma unroll
            for (int kc = 0; kc < 2; ++kc) {
                int arow = 16 * wq + l15;
                int cg = 4 * kc + l4;
                short8 af = *reinterpret_cast<const short8*>(&As[arow * 64 + ((cg ^ (arow & 7)) << 3)]);
                #pragma unroll
                for (int q = 0; q < 4; ++q) {
                    int wrow = 64 * half + 16 * q + l15;
                    short8 wf = *reinterpret_cast<const short8*>(&Ws[wrow * 64 + ((cg ^ (wrow & 7)) << 3)]);
                    acc[q] = __builtin_amdgcn_mfma_f32_16x16x32_bf16(af, wf, acc[q], 0, 0, 0);
                }
            }
            __syncthreads();
        }
        #pragma unroll
        for (int q = 0; q < 4; ++q) {
            #pragma unroll
            for (int j = 0; j < 4; ++j) {
                int m = 16 * wq + 4 * l4 + j;
                int n = n0 + 64 * half + 16 * q + l15;
                float bias = (n < 2048) ? fbb[n] : 0.f;
                projP[m * 4096 + n] = acc[q][j] + bias;
            }
        }
    }
}

// ---------------------------------------------------------------------------
// Step kernel B (32 blocks x 256 threads):
// gates GEMM M=64, N=64/block (gate-interleaved), K=2560 full:
//   A = [embA_t (512) | sigmoid(gate_raw) * awe (2048)]  (built in staging)
//   W rows = 512*q + 16*nb + j  -> thread ends with all 4 gates of one (b,d)
// Epilogue: += biasg + whh-part(projP[:,2048:]); LSTM cell update; h/c/allH.
// ---------------------------------------------------------------------------
__global__ __launch_bounds__(256)
void kStepB(const short* __restrict__ embA, const short* __restrict__ awe16,
            const float* __restrict__ projP, const short* __restrict__ wih16,
            const float* __restrict__ biasg, float* __restrict__ hc,
            short* __restrict__ h16, short* __restrict__ allH, int t)
{
    __shared__ short As[64 * 64];
    __shared__ short Ws[64 * 64];
    const int nb = blockIdx.x, tid = threadIdx.x;
    const int w = tid >> 6, l = tid & 63;
    const int l4 = l >> 4, l15 = l & 15;
    floatx4 acc[4] = {};

    for (int ks = 0; ks < 40; ++ks) {
        int kt = ks * 64;
        #pragma unroll
        for (int i = 0; i < 2; ++i) {
            int s = tid + i * 256, row = s >> 3, cg = s & 7;
            int c0 = kt + cg * 8;
            union { short s[8]; int4v v; } u8;
            if (kt < 512) {
                u8.v = *reinterpret_cast<const int4v*>(&embA[((size_t)t * 64 + row) * 512 + c0]);
            } else {
                int c = c0 - 512;
                short8 aw = *reinterpret_cast<const short8*>(&awe16[row * CENC + c]);
                float4 g0 = *reinterpret_cast<const float4*>(&projP[row * 4096 + c]);
                float4 g1 = *reinterpret_cast<const float4*>(&projP[row * 4096 + c + 4]);
                u8.s[0] = f2bf(bf2f(aw[0]) * fsigmoid(g0.x));
                u8.s[1] = f2bf(bf2f(aw[1]) * fsigmoid(g0.y));
                u8.s[2] = f2bf(bf2f(aw[2]) * fsigmoid(g0.z));
                u8.s[3] = f2bf(bf2f(aw[3]) * fsigmoid(g0.w));
                u8.s[4] = f2bf(bf2f(aw[4]) * fsigmoid(g1.x));
                u8.s[5] = f2bf(bf2f(aw[5]) * fsigmoid(g1.y));
                u8.s[6] = f2bf(bf2f(aw[6]) * fsigmoid(g1.z));
                u8.s[7] = f2bf(bf2f(aw[7]) * fsigmoid(g1.w));
            }
            *reinterpret_cast<int4v*>(&As[row * 64 + ((cg ^ (row & 7)) << 3)]) = u8.v;
        }
        #pragma unroll
        for (int i = 0; i < 2; ++i) {
            int s = tid + i * 256, r = s >> 3, cg = s & 7;
            int wr = 512 * (r >> 4) + 16 * nb + (r & 15);
            int4v v = *reinterpret_cast<const int4v*>(&wih16[(size_t)wr * 2560 + kt + cg * 8]);
            *reinterpret_cast<int4v*>(&Ws[r * 64 + ((cg ^ (r & 7)) << 3)]) = v;
        }
        __syncthreads();
        #pragma unroll
        for (int kc = 0; kc < 2; ++kc) {
            int arow = 16 * w + l15;
            int cg = 4 * kc + l4;
            short8 af = *reinterpret_cast<const short8*>(&As[arow * 64 + ((cg ^ (arow & 7)) << 3)]);
            #pragma unroll
            for (int q = 0; q < 4; ++q) {
                int wrow = 16 * q + l15;
                short8 wf = *reinterpret_cast<const short8*>(&Ws[wrow * 64 + ((cg ^ (wrow & 7)) << 3)]);
                acc[q] = __builtin_amdgcn_mfma_f32_16x16x32_bf16(af, wf, acc[q], 0, 0, 0);
            }
        }
        __syncthreads();
    }

    // LSTM epilogue: thread holds gates q=0..3 for batches m (4 j's), dim d
    const int d = 16 * nb + l15;
    #pragma unroll
    for (int j = 0; j < 4; ++j) {
        int m = 16 * w + 4 * l4 + j;
        float g0 = acc[0][j] + biasg[0 * 512 + d] + projP[m * 4096 + 2048 + 0 * 512 + d];
        float g1 = acc[1][j] + biasg[1 * 512 + d] + projP[m * 4096 + 2048 + 1 * 512 + d];
        float g2 = acc[2][j] + biasg[2 * 512 + d] + projP[m * 4096 + 2048 + 2 * 512 + d];
        float g3 = acc[3][j] + biasg[3 * 512 + d] + projP[m * 4096 + 2048 + 3 * 512 + d];
        float i_ = fsigmoid(g0);
        float f_ = fsigmoid(g1);
        float gg = tanhf(g2);
        float o_ = fsigmoid(g3);
        float c_new = f_ * hc[m * 1024 + 512 + d] + i_ * gg;
        float h_new = o_ * tanhf(c_new);
        hc[m * 1024 + 512 + d] = c_new;
        short hb = f2bf(h_new);
        h16[m * 512 + d] = hb;
        allH[((size_t)t * 64 + m) * 512 + d] = hb;
    }
}

extern "C" void kernel_launch(void* const* d_in, const int* in_sizes, int n_in,
                              void* d_out, int out_size, void* d_ws, size_t ws_size,
                              hipStream_t stream)
{
    const float* enc        = (const float*)d_in[0];
    const int*   captions   = (const int*)d_in[1];
    const int*   lengths    = (const int*)d_in[2];
    const float* enc_att_w  = (const float*)d_in[3];
    const float* enc_att_b  = (const float*)d_in[4];
    const float* hid_att_w  = (const float*)d_in[5];
    const float* hid_att_b  = (const float*)d_in[6];
    const float* full_att_w = (const float*)d_in[7];
    const float* full_att_b = (const float*)d_in[8];
    const float* embw       = (const float*)d_in[9];
    const float* w_ih       = (const float*)d_in[10];
    const float* w_hh       = (const float*)d_in[11];
    const float* b_ih       = (const float*)d_in[12];
    const float* b_hh       = (const float*)d_in[13];
    const float* init_h_w   = (const float*)d_in[14];
    const float* init_h_b   = (const float*)d_in[15];
    const float* init_c_w   = (const float*)d_in[16];
    const float* init_c_b   = (const float*)d_in[17];
    const float* fbeta_w    = (const float*)d_in[18];
    const float* fbeta_b    = (const float*)d_in[19];
    const float* fc_w       = (const float*)d_in[20];
    const float* fc_b       = (const float*)d_in[21];

    float* out_pred  = (float*)d_out;                        // [64][19][10000]
    float* out_alpha = out_pred + (size_t)BB * TM1 * VV;     // [64][19][196]

    // ---- scratch in d_out pred region (dead before pred GEMM; 34.3MB < 48.6MB)
    char* pr = (char*)d_out;
    short* att1_16 = (short*)pr;  pr += 12845056;  // 12544x512 bf16
    short* wih16   = (short*)pr;  pr += 10485760;  // 2048x2560 bf16
    short* projW16 = (short*)pr;  pr += 4194304;   // 4096x512 bf16
    short* hidattT = (short*)pr;  pr += 524288;    // 512x512 bf16
    float* projP   = (float*)pr;  pr += 1048576;   // 64x4096 f32
    short* awe16   = (short*)pr;  pr += 262144;    // 64x2048 bf16
    short* embA    = (short*)pr;  pr += 1245184;   // 1216x512 bf16
    short* encw16  = (short*)pr;  pr += 2097152;   // 512x2048 bf16 (dead after att1)
    float* mean    = (float*)pr;  pr += 524288;    // dead after init
    float* hcP     = (float*)pr;  pr += 1048576;   // dead after init

    // ---- workspace (~63MB)
    char* wp = (char*)d_ws;
    float* hc    = (float*)wp;  wp += 262144;      // 64x1024 f32 (c in [:,512:])
    short* h16   = (short*)wp;  wp += 65536;       // 64x512 bf16
    short* allH  = (short*)wp;  wp += 1245184;     // 19x64x512 bf16
    short* fc16  = (short*)wp;  wp += 10240000;    // 10000x512 bf16
    float* biasg = (float*)wp;  wp += 8192;        // 2048 f32
    short* enc16 = (short*)wp;  wp += 51380224;    // 64x196x2048 bf16 (optional)
    const bool full = ((size_t)(wp - (char*)d_ws) <= ws_size);

    // ---- precompute ----
    kPrepW<<<6725, 256, 0, stream>>>(enc_att_w, hid_att_w, fbeta_w, w_hh, w_ih, fc_w,
                                     b_ih, b_hh,
                                     encw16, projW16, wih16, fc16, hidattT, biasg);
    if (full) kMeanEnc<1><<<dim3(64, 8), 256, 0, stream>>>(enc, enc16, mean);
    else      kMeanEnc<0><<<dim3(64, 8), 256, 0, stream>>>(enc, enc16, mean);
    kEmbGather<<<304, 256, 0, stream>>>(embw, captions, embA);
    gemmInit<<<dim3(16, 1, 4), 256, 0, stream>>>(mean, init_h_w, init_c_w, hcP);
    kReduceHC<<<64, 256, 0, stream>>>(hcP, init_h_b, init_c_b, hc, h16);

    // att1 = enc @ enc_att_w^T + b -> bf16 [12544][512]
    if (full)
        kGemm<0, 1, 1><<<1568, 256, 0, stream>>>(enc16, CENC, encw16, CENC,
            enc_att_b, 512, nullptr, 512, att1_16, 32, nullptr);
    else
        kGemm<1, 1, 1><<<1568, 256, 0, stream>>>(enc, CENC, encw16, CENC,
            enc_att_b, 512, nullptr, 512, att1_16, 32, nullptr);

    // ---- sequential decode: 2 kernels per step ----
    for (int t = 0; t < TM1; ++t) {
        if (full)
            kStepA<1><<<96, 512, 0, stream>>>(h16, hidattT, hid_att_b, att1_16,
                full_att_w, full_att_b, lengths, projW16, fbeta_b, enc16,
                projP, awe16, out_alpha, t);
        else
            kStepA<0><<<96, 512, 0, stream>>>(h16, hidattT, hid_att_b, att1_16,
                full_att_w, full_att_b, lengths, projW16, fbeta_b, enc,
                projP, awe16, out_alpha, t);

        kStepB<<<32, 256, 0, stream>>>(embA, awe16, projP, wih16, biasg,
                                       hc, h16, allH, t);
    }

    // ---- pred = allH @ fc_w^T + fc_b (masked, remapped) ----
    kGemm<0, 2, 2><<<3040, 256, 0, stream>>>(allH, 512, fc16, 512,
        fc_b, VV, out_pred, VV, nullptr, 8, lengths);
}

// Round 5
// 1333.614 us; speedup vs baseline: 5.4134x; 1.8364x over previous
//
#include <hip/hip_runtime.h>
#include <hip/hip_bf16.h>

typedef short short8  __attribute__((ext_vector_type(8)));
typedef float floatx4 __attribute__((ext_vector_type(4)));
typedef int   int4v   __attribute__((ext_vector_type(4)));

constexpr int BB = 64, PP = 196, CENC = 2048, HH = 512, AA = 512, EE = 512;
constexpr int VV = 10000, TT = 20, TM1 = 19;
constexpr int NCAT = 4608;  // 512 (att) + 2048 (fbeta) + 2048 (Whh)

__device__ __forceinline__ float bf2f(short u) {
    union { unsigned u; float f; } v; v.u = ((unsigned)(unsigned short)u) << 16; return v.f;
}
__device__ __forceinline__ short f2bf(float f) {
    union { float f; unsigned u; } v; v.f = f;
    unsigned r = v.u + 0x7FFF + ((v.u >> 16) & 1);
    return (short)(r >> 16);
}

// async global->LDS, 16B per lane; LDS dest = wave-uniform base + lane*16
#define GLL(gp, lp) __builtin_amdgcn_global_load_lds( \
    (const __attribute__((address_space(1))) void*)(gp), \
    (__attribute__((address_space(3))) void*)(lp), 16, 0, 0)

// ---------------------------------------------------------------------------
// Weight prep: f32 -> bf16 conversions + concatenations + bias builds.
// ---------------------------------------------------------------------------
__global__ __launch_bounds__(256)
void kPrepW(const float* __restrict__ encw_s, const float* __restrict__ haw,
            const float* __restrict__ fbw, const float* __restrict__ whh,
            const float* __restrict__ wih, const float* __restrict__ fcw,
            const float* __restrict__ hab, const float* __restrict__ fbb,
            const float* __restrict__ bih, const float* __restrict__ bhh,
            short* __restrict__ encw_d, short* __restrict__ wcat_d,
            short* __restrict__ wihe_d, short* __restrict__ wihm_d,
            short* __restrict__ fc_d, float* __restrict__ biascat,
            float* __restrict__ biasg)
{
    long e = ((long)blockIdx.x * 256 + threadIdx.x) * 8;
    const float* sp = nullptr; short* dp = nullptr; long de = 0;
    if (e < 1048576)       { sp = &encw_s[e]; dp = encw_d; de = e; }
    else if (e < 3407872)  { long u = e - 1048576; long row = u >> 9, col = u & 511;
                             sp = (row < 512) ? &haw[row * 512 + col]
                                : (row < 2560) ? &fbw[(row - 512) * 512 + col]
                                               : &whh[(row - 2560) * 512 + col];
                             dp = wcat_d; de = u; }
    else if (e < 7602176)  { long u = e - 3407872; long row = u >> 11, col = u & 2047;
                             sp = &wih[row * 2560 + 512 + col]; dp = wihe_d; de = u; }
    else if (e < 8650752)  { long u = e - 7602176; long row = u >> 9, col = u & 511;
                             sp = &wih[row * 2560 + col]; dp = wihm_d; de = u; }
    else if (e < 13770752) { long u = e - 8650752; sp = &fcw[u]; dp = fc_d; de = u; }
    else if (e < 13775360) { long u = e - 13770752;
                             for (int j = 0; j < 8; ++j) { long w = u + j;
                                 biascat[w] = (w < 512) ? hab[w] : ((w < 2560) ? fbb[w - 512] : 0.f); }
                             return; }
    else if (e < 13777408) { long u = e - 13775360;
                             for (int j = 0; j < 8; ++j) biasg[u + j] = bih[u + j] + bhh[u + j];
                             return; }
    else return;
    union { short s[8]; int4v v; } u8;
    #pragma unroll
    for (int j = 0; j < 8; ++j) u8.s[j] = f2bf(sp[j]);
    *reinterpret_cast<int4v*>(&dp[de]) = u8.v;
}

// p-split mean partials + enc f32->bf16. grid (64, 8, 7): 28 rows per z-block.
template<int FULL>
__global__ __launch_bounds__(256)
void kMeanEnc(const float* __restrict__ enc, short* __restrict__ enc16,
              float* __restrict__ meanP)
{
    int b = blockIdx.x, kc = blockIdx.y, pz = blockIdx.z;
    int k = kc * 256 + threadIdx.x;
    const float* eb = &enc[((size_t)b * PP + pz * 28) * CENC + k];
    short* ob = &enc16[((size_t)b * PP + pz * 28) * CENC + k];
    float s0 = 0, s1 = 0, s2 = 0, s3 = 0;
    for (int p = 0; p < 28; p += 4) {
        float v0 = eb[(size_t)(p + 0) * CENC], v1 = eb[(size_t)(p + 1) * CENC];
        float v2 = eb[(size_t)(p + 2) * CENC], v3 = eb[(size_t)(p + 3) * CENC];
        s0 += v0; s1 += v1; s2 += v2; s3 += v3;
        if (FULL) {
            ob[(size_t)(p + 0) * CENC] = f2bf(v0); ob[(size_t)(p + 1) * CENC] = f2bf(v1);
            ob[(size_t)(p + 2) * CENC] = f2bf(v2); ob[(size_t)(p + 3) * CENC] = f2bf(v3);
        }
    }
    meanP[((size_t)pz * 64 + b) * 2048 + k] = (s0 + s1) + (s2 + s3);
}

// embedding gather -> embA[r = t*64+b][512] bf16
__global__ __launch_bounds__(256)
void kEmbGather(const float* __restrict__ embw, const int* __restrict__ captions,
                short* __restrict__ embA)
{
    long e = ((long)blockIdx.x * 256 + threadIdx.x) * 8;
    int r = (int)(e >> 9), j = (int)(e & 511);
    int t = r >> 6, b = r & 63;
    int tok = captions[b * TT + t];
    const float* sp = &embw[(size_t)tok * EE + j];
    union { short s[8]; int4v v; } u8;
    #pragma unroll
    for (int q = 0; q < 8; ++q) u8.s[q] = f2bf(sp[q]);
    *reinterpret_cast<int4v*>(&embA[e]) = u8.v;
}

// ---------------------------------------------------------------------------
// MFMA bf16 GEMM: C[M,N] = A[M,K] @ W[N,K]^T. Tile 64x64, BK=64, 4 waves.
// bf16 staging uses global_load_lds (linear LDS dest, inverse-XOR global src);
// MFMA reads apply the XOR -> conflict-free and zero VGPR round-trip.
// AOP: 0 = A bf16 (gll); 1 = A f32 (register convert staging)
// WOP: 0 = plain row n0+r (bounds vs Ntot); 1 = gate-interleaved LSTM rows
// EOP: 0 = f32 +bias; 1 = bf16 +bias; 2 = pred (mask/remap); 4 = k-partials
// SWZ: 0 = (x,y,z)=(nb,mb,kz); 1 = att1 XCD swizzle; 2 = pred swizzle
// ---------------------------------------------------------------------------
template<int AOP, int WOP, int EOP, int SWZ>
__global__ __launch_bounds__(256)
void kGemm(const void* __restrict__ Ap, int lda, const short* __restrict__ W, int ldw,
           const float* __restrict__ bias, int Ntot,
           float* __restrict__ outF, int ldc, short* __restrict__ outB,
           int nk, const int* __restrict__ lengths)
{
    __shared__ short As[64 * 64];
    __shared__ short Ws[64 * 64];
    int nb, mb, kz;
    if (SWZ == 0) { nb = blockIdx.x; mb = blockIdx.y; kz = blockIdx.z; }
    else if (SWZ == 1) {  // att1: 1568 blocks, group 8 same-A n-blocks per XCD
        int j = blockIdx.x;
        if (j < 1536) { mb = (j >> 6) * 8 + (j & 7); nb = (j >> 3) & 7; }
        else          { int u = j - 1536; mb = 192 + (u >> 3); nb = u & 7; }
        kz = 0;
    } else {              // pred: 3040 blocks
        int j = blockIdx.x; int c = j & 7, s = j >> 3;
        mb = s % 19; int u = s / 19; nb = 8 * u + c; kz = 0;
        if (nb * 64 >= Ntot) return;
    }
    const int tid = threadIdx.x;
    const int m0 = mb * 64, n0 = nb * 64, k0 = kz * nk * 64;
    const int w = tid >> 6, l = tid & 63;
    floatx4 acc[4] = {};

    for (int ks = 0; ks < nk; ++ks) {
        int kt = k0 + ks * 64;
        // ---- stage A ----
        if (AOP == 0) {
            const short* A = (const short*)Ap;
            #pragma unroll
            for (int i = 0; i < 2; ++i) {
                int ii = w * 2 + i;                 // 8 x 1KB slots
                int row = ii * 8 + (l >> 3);
                int cg = l & 7;
                const short* gp = &A[(size_t)(m0 + row) * lda + kt + ((cg ^ (row & 7)) << 3)];
                GLL(gp, &As[ii * 512]);
            }
        } else {
            const float* A = (const float*)Ap;
            #pragma unroll
            for (int i = 0; i < 2; ++i) {
                int s = tid + i * 256, row = s >> 3, cg = s & 7;
                const float* sp = &A[(size_t)(m0 + row) * lda + kt + cg * 8];
                float4 a = *reinterpret_cast<const float4*>(sp);
                float4 b = *reinterpret_cast<const float4*>(sp + 4);
                union { short s[8]; int4v v; } u8;
                u8.s[0]=f2bf(a.x); u8.s[1]=f2bf(a.y); u8.s[2]=f2bf(a.z); u8.s[3]=f2bf(a.w);
                u8.s[4]=f2bf(b.x); u8.s[5]=f2bf(b.y); u8.s[6]=f2bf(b.z); u8.s[7]=f2bf(b.w);
                *reinterpret_cast<int4v*>(&As[row * 64 + ((cg ^ (row & 7)) << 3)]) = u8.v;
            }
        }
        // ---- stage W (gll) ----
        #pragma unroll
        for (int i = 0; i < 2; ++i) {
            int ii = w * 2 + i;
            int r = ii * 8 + (l >> 3);
            int cg = l & 7;
            int wr;
            if (WOP == 1) wr = 512 * (r >> 4) + 16 * nb + (r & 15);
            else          wr = n0 + r;
            if (WOP == 1 || wr < Ntot) {
                const short* gp = &W[(size_t)wr * ldw + kt + ((cg ^ (r & 7)) << 3)];
                GLL(gp, &Ws[ii * 512]);
            }
        }
        __syncthreads();
        // ---- MFMA ----
        #pragma unroll
        for (int kc = 0; kc < 2; ++kc) {
            int arow = 16 * w + (l & 15);
            int cg = 4 * kc + (l >> 4);
            short8 af = *reinterpret_cast<const short8*>(&As[arow * 64 + ((cg ^ (arow & 7)) << 3)]);
            #pragma unroll
            for (int q = 0; q < 4; ++q) {
                int wrow = 16 * q + (l & 15);
                short8 wf = *reinterpret_cast<const short8*>(&Ws[wrow * 64 + ((cg ^ (wrow & 7)) << 3)]);
                acc[q] = __builtin_amdgcn_mfma_f32_16x16x32_bf16(af, wf, acc[q], 0, 0, 0);
            }
        }
        __syncthreads();
    }
    // ---- epilogue ----
    int l4 = l >> 4, l15 = l & 15;
    #pragma unroll
    for (int q = 0; q < 4; ++q) {
        #pragma unroll
        for (int j = 0; j < 4; ++j) {
            int m = m0 + 16 * w + 4 * l4 + j;
            int n = n0 + 16 * q + l15;
            float val = acc[q][j];
            if (EOP == 0) {
                outF[(size_t)m * ldc + n] = val + bias[n];
            } else if (EOP == 1) {
                outB[(size_t)m * ldc + n] = f2bf(val + bias[n]);
            } else if (EOP == 2) {
                if (n < Ntot) {
                    int b = m & 63, tt = m >> 6;
                    bool act = tt < (lengths[b] - 1);
                    outF[((size_t)b * TM1 + tt) * VV + n] = act ? (val + bias[n]) : 0.f;
                }
            } else { // EOP == 4: gate-layout partials: col = 512q + 16nb + l15
                int col = 512 * q + (n0 >> 2) + l15;
                int mloc = m - m0;
                outF[((size_t)kz * 64 + mloc) * 2048 + col] = val;
            }
        }
    }
}

// f32 init GEMM: h0|c0 partials from mean (reduces 7 meanP partials in staging)
__global__ __launch_bounds__(256)
void gemmInit(const float* __restrict__ meanP, const float* __restrict__ W1,
              const float* __restrict__ W2, float* __restrict__ C)
{
    __shared__ __align__(16) float As_[32][64];
    __shared__ __align__(16) float Ws_[32][64];
    const int tid = threadIdx.x;
    const int n0 = blockIdx.x * 64, kz = blockIdx.z, k0 = kz * 512;
    const int ty = tid >> 4, tx = tid & 15;
    float acc[4][4] = {};
    for (int kt = k0; kt < k0 + 512; kt += 32) {
        #pragma unroll
        for (int i = 0; i < 2; ++i) {
            int idx = tid + i * 256, row = idx >> 3, c4 = (idx & 7) * 4;
            float4 v = make_float4(0.f, 0.f, 0.f, 0.f);
            #pragma unroll
            for (int pz = 0; pz < 7; ++pz) {
                float4 u = *reinterpret_cast<const float4*>(
                    &meanP[((size_t)pz * 64 + row) * CENC + kt + c4]);
                v.x += u.x; v.y += u.y; v.z += u.z; v.w += u.w;
            }
            const float inv = 1.0f / PP;
            As_[c4 + 0][row] = v.x * inv; As_[c4 + 1][row] = v.y * inv;
            As_[c4 + 2][row] = v.z * inv; As_[c4 + 3][row] = v.w * inv;
        }
        #pragma unroll
        for (int i = 0; i < 2; ++i) {
            int idx = tid + i * 256, row = idx >> 3, c4 = (idx & 7) * 4;
            int n = n0 + row;
            const float* wr = (n < 512) ? &W1[(size_t)n * CENC + kt + c4]
                                        : &W2[(size_t)(n - 512) * CENC + kt + c4];
            float4 v = *reinterpret_cast<const float4*>(wr);
            Ws_[c4 + 0][row] = v.x; Ws_[c4 + 1][row] = v.y; Ws_[c4 + 2][row] = v.z; Ws_[c4 + 3][row] = v.w;
        }
        __syncthreads();
        #pragma unroll
        for (int kk = 0; kk < 32; ++kk) {
            float av[4], bv[4];
            *reinterpret_cast<float4*>(av) = *reinterpret_cast<const float4*>(&As_[kk][ty * 4]);
            *reinterpret_cast<float4*>(bv) = *reinterpret_cast<const float4*>(&Ws_[kk][tx * 4]);
            #pragma unroll
            for (int ii = 0; ii < 4; ++ii)
                #pragma unroll
                for (int jj = 0; jj < 4; ++jj)
                    acc[ii][jj] = fmaf(av[ii], bv[jj], acc[ii][jj]);
        }
        __syncthreads();
    }
    #pragma unroll
    for (int ii = 0; ii < 4; ++ii)
        #pragma unroll
        for (int jj = 0; jj < 4; ++jj)
            C[((size_t)kz * 64 + ty * 4 + ii) * 1024 + n0 + tx * 4 + jj] = acc[ii][jj];
}

__global__ __launch_bounds__(256)
void kReduceHC(const float* __restrict__ Pc, const float* __restrict__ hb,
               const float* __restrict__ cb, float* __restrict__ hc,
               short* __restrict__ h16)
{
    int b = blockIdx.x, tid = threadIdx.x;
    for (int j = tid; j < 1024; j += 256) {
        float s = Pc[((size_t)0 * BB + b) * 1024 + j] + Pc[((size_t)1 * BB + b) * 1024 + j]
                + Pc[((size_t)2 * BB + b) * 1024 + j] + Pc[((size_t)3 * BB + b) * 1024 + j];
        s += (j < 512) ? hb[j] : cb[j - 512];
        hc[b * 1024 + j] = s;
        if (j < 512) h16[b * 512 + j] = f2bf(s);
    }
}

// ---------------------------------------------------------------------------
// Step B: e = relu(att1 + att2) @ faw + fab; softmax -> alpha (+ masked out)
// ---------------------------------------------------------------------------
__global__ __launch_bounds__(256)
void kStepB(const short* __restrict__ att1, const float* __restrict__ P3h,
            const float* __restrict__ faw, const float* __restrict__ fab,
            const int* __restrict__ lengths, float* __restrict__ alpha,
            float* __restrict__ alpha_out, int t)
{
    int b = blockIdx.x, tid = threadIdx.x;
    __shared__ float att2s[512];
    __shared__ float fw[512];
    __shared__ float es[PP];
    __shared__ float red[8];
    for (int a = tid; a < 512; a += 256) { att2s[a] = P3h[b * NCAT + a]; fw[a] = faw[a]; }
    __syncthreads();
    int wv = tid >> 6, lane = tid & 63;
    for (int p = wv; p < PP; p += 4) {
        short8 v = *reinterpret_cast<const short8*>(&att1[((size_t)b * PP + p) * 512 + lane * 8]);
        float s = 0.f;
        #pragma unroll
        for (int j = 0; j < 8; ++j) {
            float x = bf2f(v[j]) + att2s[lane * 8 + j];
            s += fmaxf(x, 0.f) * fw[lane * 8 + j];
        }
        #pragma unroll
        for (int off = 32; off > 0; off >>= 1) s += __shfl_down(s, off, 64);
        if (lane == 0) es[p] = s + fab[0];
    }
    __syncthreads();
    float m = -1e30f;
    for (int p = tid; p < PP; p += 256) m = fmaxf(m, es[p]);
    #pragma unroll
    for (int off = 32; off > 0; off >>= 1) m = fmaxf(m, __shfl_down(m, off, 64));
    if (lane == 0) red[wv] = m;
    __syncthreads();
    m = fmaxf(fmaxf(red[0], red[1]), fmaxf(red[2], red[3]));
    float ssum = 0.f;
    for (int p = tid; p < PP; p += 256) { float ev = __expf(es[p] - m); es[p] = ev; ssum += ev; }
    #pragma unroll
    for (int off = 32; off > 0; off >>= 1) ssum += __shfl_down(ssum, off, 64);
    if (lane == 0) red[4 + wv] = ssum;
    __syncthreads();
    float inv = 1.f / (red[4] + red[5] + red[6] + red[7]);
    bool active = t < (lengths[b] - 1);
    for (int p = tid; p < PP; p += 256) {
        float al = es[p] * inv;
        alpha[b * PP + p] = al;
        alpha_out[((size_t)b * TM1 + t) * PP + p] = active ? al : 0.f;
    }
}

// ---------------------------------------------------------------------------
// Step C: awe = alpha @ enc[b]; x = sigmoid(gate_raw) * awe -> bf16
// grid (64, 8): block (b, kc), 256 cols each.
// ---------------------------------------------------------------------------
template<int BF>
__global__ __launch_bounds__(256)
void kStepC(const void* __restrict__ encp, const float* __restrict__ alpha,
            const float* __restrict__ P3h, short* __restrict__ x16)
{
    int b = blockIdx.x, kc = blockIdx.y, tid = threadIdx.x;
    __shared__ float al[PP];
    __shared__ float part[8][256];
    for (int p = tid; p < PP; p += 256) al[p] = alpha[b * PP + p];
    __syncthreads();
    if (BF == 1) {
        const short* enc16 = (const short*)encp;
        int g = tid & 31, prow = tid >> 5;      // 8 cols/thread, 8 p-lanes
        int k0 = kc * 256 + g * 8;
        float acc[8] = {};
        for (int p = prow; p < PP; p += 8) {
            short8 v = *reinterpret_cast<const short8*>(&enc16[((size_t)b * PP + p) * CENC + k0]);
            float a_ = al[p];
            #pragma unroll
            for (int j = 0; j < 8; ++j) acc[j] = fmaf(bf2f(v[j]), a_, acc[j]);
        }
        *reinterpret_cast<float4*>(&part[prow][g * 8])     = make_float4(acc[0], acc[1], acc[2], acc[3]);
        *reinterpret_cast<float4*>(&part[prow][g * 8 + 4]) = make_float4(acc[4], acc[5], acc[6], acc[7]);
        __syncthreads();
        int c = tid;
        float awe = 0.f;
        #pragma unroll
        for (int pr = 0; pr < 8; ++pr) awe += part[pr][c];
        int k = kc * 256 + c;
        float gate = 1.f / (1.f + __expf(-P3h[b * NCAT + 512 + k]));
        x16[(size_t)b * CENC + k] = f2bf(gate * awe);
    } else {
        const float* enc = (const float*)encp;
        int g = tid & 63, prow = tid >> 6;      // 4 cols/thread, 4 p-lanes
        int k0 = kc * 256 + g * 4;
        float acc[4] = {};
        for (int p = prow; p < PP; p += 4) {
            float4 v = *reinterpret_cast<const float4*>(&enc[((size_t)b * PP + p) * CENC + k0]);
            float a_ = al[p];
            acc[0] = fmaf(v.x, a_, acc[0]); acc[1] = fmaf(v.y, a_, acc[1]);
            acc[2] = fmaf(v.z, a_, acc[2]); acc[3] = fmaf(v.w, a_, acc[3]);
        }
        *reinterpret_cast<float4*>(&part[prow][g * 4]) = make_float4(acc[0], acc[1], acc[2], acc[3]);
        __syncthreads();
        int c = tid;
        float awe = part[0][c] + part[1][c] + part[2][c] + part[3][c];
        int k = kc * 256 + c;
        float gate = 1.f / (1.f + __expf(-P3h[b * NCAT + 512 + k]));
        x16[(size_t)b * CENC + k] = f2bf(gate * awe);
    }
}

// ---------------------------------------------------------------------------
// Step D2: reduce gate partials (4 chunks) + emb part + Whh part; LSTM update.
// ---------------------------------------------------------------------------
__global__ __launch_bounds__(256)
void kStepD2(const float* __restrict__ Pg, const float* __restrict__ gates_emb,
             const float* __restrict__ P3h, float* __restrict__ hc,
             short* __restrict__ h16, short* __restrict__ allH, int t)
{
    int b = blockIdx.x, tid = threadIdx.x;
    for (int d = tid; d < 512; d += 256) {
        float g4[4];
        #pragma unroll
        for (int q = 0; q < 4; ++q) {
            int col = q * 512 + d;
            float s = gates_emb[((size_t)t * 64 + b) * 2048 + col] + P3h[b * NCAT + 2560 + col];
            #pragma unroll
            for (int kz = 0; kz < 4; ++kz) s += Pg[((size_t)kz * 64 + b) * 2048 + col];
            g4[q] = s;
        }
        float i_ = 1.f / (1.f + __expf(-g4[0]));
        float f_ = 1.f / (1.f + __expf(-g4[1]));
        float g_ = tanhf(g4[2]);
        float o_ = 1.f / (1.f + __expf(-g4[3]));
        float c_new = f_ * hc[b * 1024 + 512 + d] + i_ * g_;
        float h_new = o_ * tanhf(c_new);
        hc[b * 1024 + 512 + d] = c_new;
        hc[b * 1024 + d] = h_new;
        short hb = f2bf(h_new);
        h16[b * 512 + d] = hb;
        allH[((size_t)t * 64 + b) * 512 + d] = hb;
    }
}

extern "C" void kernel_launch(void* const* d_in, const int* in_sizes, int n_in,
                              void* d_out, int out_size, void* d_ws, size_t ws_size,
                              hipStream_t stream)
{
    const float* enc        = (const float*)d_in[0];
    const int*   captions   = (const int*)d_in[1];
    const int*   lengths    = (const int*)d_in[2];
    const float* enc_att_w  = (const float*)d_in[3];
    const float* enc_att_b  = (const float*)d_in[4];
    const float* hid_att_w  = (const float*)d_in[5];
    const float* hid_att_b  = (const float*)d_in[6];
    const float* full_att_w = (const float*)d_in[7];
    const float* full_att_b = (const float*)d_in[8];
    const float* embw       = (const float*)d_in[9];
    const float* w_ih       = (const float*)d_in[10];
    const float* w_hh       = (const float*)d_in[11];
    const float* b_ih       = (const float*)d_in[12];
    const float* b_hh       = (const float*)d_in[13];
    const float* init_h_w   = (const float*)d_in[14];
    const float* init_h_b   = (const float*)d_in[15];
    const float* init_c_w   = (const float*)d_in[16];
    const float* init_c_b   = (const float*)d_in[17];
    const float* fbeta_w    = (const float*)d_in[18];
    const float* fbeta_b    = (const float*)d_in[19];
    const float* fc_w       = (const float*)d_in[20];
    const float* fc_b       = (const float*)d_in[21];

    float* out_pred  = (float*)d_out;                        // [64][19][10000]
    float* out_alpha = out_pred + (size_t)BB * TM1 * VV;     // [64][19][196]

    // ---- scratch in d_out pred region (all < 48.64MB, dead before pred GEMM)
    char* pr = (char*)d_out;
    short* att1_16   = (short*)pr;  pr += 12845056;  // live in loop
    float* gates_emb = (float*)pr;  pr += 9961472;   // live
    short* wcat16    = (short*)pr;  pr += 4718592;   // live
    short* wihe16    = (short*)pr;  pr += 8388608;   // live
    float* biascat   = (float*)pr;  pr += 18432;     // live
    float* P3h       = (float*)pr;  pr += 1179648;   // live (loop)
    float* Pg        = (float*)pr;  pr += 2097152;   // live (loop)
    short* embA      = (short*)pr;  pr += 1245184;   // precompute only
    short* wihm16    = (short*)pr;  pr += 2097152;   // precompute only
    short* encw16    = (short*)pr;  pr += 2097152;   // dead after att1
    float* biasg     = (float*)pr;  pr += 8192;      // precompute only
    float* meanP     = (float*)pr;  pr += 3670016;   // dead after gemmInit
    float* hcP       = (float*)pr;  pr += 1048576;   // dead after kReduceHC

    // ---- workspace
    char* wp = (char*)d_ws;
    float* hc    = (float*)wp;  wp += 262144;      // 64x1024 f32
    short* h16   = (short*)wp;  wp += 65536;       // 64x512 bf16
    short* x16   = (short*)wp;  wp += 262144;      // 64x2048 bf16
    float* alpha = (float*)wp;  wp += 50176;       // 64x196 f32
    short* fc16  = (short*)wp;  wp += 10240000;    // 10000x512 bf16
    short* allH  = (short*)wp;  wp += 1245184;     // 19x64x512 bf16
    short* enc16 = (short*)wp;  wp += 51380224;    // 64x196x2048 bf16 (optional)
    const bool full = ((size_t)(wp - (char*)d_ws) <= ws_size);

    // ---- precompute ----
    kPrepW<<<6728, 256, 0, stream>>>(enc_att_w, hid_att_w, fbeta_w, w_hh, w_ih, fc_w,
                                     hid_att_b, fbeta_b, b_ih, b_hh,
                                     encw16, wcat16, wihe16, wihm16, fc16, biascat, biasg);
    if (full) kMeanEnc<1><<<dim3(64, 8, 7), 256, 0, stream>>>(enc, enc16, meanP);
    else      kMeanEnc<0><<<dim3(64, 8, 7), 256, 0, stream>>>(enc, enc16, meanP);
    kEmbGather<<<304, 256, 0, stream>>>(embw, captions, embA);
    gemmInit<<<dim3(16, 1, 4), 256, 0, stream>>>(meanP, init_h_w, init_c_w, hcP);
    kReduceHC<<<64, 256, 0, stream>>>(hcP, init_h_b, init_c_b, hc, h16);

    // att1 = enc @ enc_att_w^T + b -> bf16 [12544][512]
    if (full)
        kGemm<0, 0, 1, 1><<<1568, 256, 0, stream>>>(enc16, CENC, encw16, CENC,
            enc_att_b, 512, nullptr, 512, att1_16, 32, nullptr);
    else
        kGemm<1, 0, 1, 1><<<1568, 256, 0, stream>>>(enc, CENC, encw16, CENC,
            enc_att_b, 512, nullptr, 512, att1_16, 32, nullptr);

    // gates_emb = embA @ W_ih[:, :512]^T + (b_ih + b_hh)  -> f32 [1216][2048]
    kGemm<0, 0, 0, 0><<<dim3(32, 19, 1), 256, 0, stream>>>(embA, 512, wihm16, 512,
        biasg, 2048, gates_emb, 2048, nullptr, 8, nullptr);

    // ---- sequential decode: 5 kernels per step (R2 structure) ----
    for (int t = 0; t < TM1; ++t) {
        // P3h = h @ [hid_att_w ; fbeta_w ; W_hh]^T + biascat  -> [64][4608]
        kGemm<0, 0, 0, 0><<<dim3(72, 1, 1), 256, 0, stream>>>(h16, 512, wcat16, 512,
            biascat, NCAT, P3h, NCAT, nullptr, 8, nullptr);

        kStepB<<<64, 256, 0, stream>>>(att1_16, P3h, full_att_w, full_att_b,
                                       lengths, alpha, out_alpha, t);

        if (full) kStepC<1><<<dim3(64, 8), 256, 0, stream>>>(enc16, alpha, P3h, x16);
        else      kStepC<0><<<dim3(64, 8), 256, 0, stream>>>(enc, alpha, P3h, x16);

        // gate partials: x @ W_ih[:, 512:]^T (gate-interleaved rows), k-split x4
        kGemm<0, 1, 4, 0><<<dim3(32, 1, 4), 256, 0, stream>>>(x16, CENC, wihe16, CENC,
            nullptr, 2048, Pg, 2048, nullptr, 8, nullptr);

        kStepD2<<<64, 256, 0, stream>>>(Pg, gates_emb, P3h, hc, h16, allH, t);
    }

    // ---- pred = allH @ fc_w^T + fc_b (masked, remapped) ----
    kGemm<0, 0, 2, 2><<<3040, 256, 0, stream>>>(allH, 512, fc16, 512,
        fc_b, VV, out_pred, VV, nullptr, 8, lengths);
}

// Round 6
// 1229.244 us; speedup vs baseline: 5.8730x; 1.0849x over previous
//
#include <hip/hip_runtime.h>
#include <hip/hip_bf16.h>

typedef short short8  __attribute__((ext_vector_type(8)));
typedef float floatx4 __attribute__((ext_vector_type(4)));
typedef int   int4v   __attribute__((ext_vector_type(4)));

constexpr int BB = 64, PP = 196, CENC = 2048, HH = 512, AA = 512, EE = 512;
constexpr int VV = 10000, TT = 20, TM1 = 19;
constexpr int NCAT = 4608;  // 512 (att) + 2048 (fbeta) + 2048 (Whh)

__device__ __forceinline__ float bf2f(short u) {
    union { unsigned u; float f; } v; v.u = ((unsigned)(unsigned short)u) << 16; return v.f;
}
__device__ __forceinline__ short f2bf(float f) {
    union { float f; unsigned u; } v; v.f = f;
    unsigned r = v.u + 0x7FFF + ((v.u >> 16) & 1);
    return (short)(r >> 16);
}

// async global->LDS, 16B per lane; LDS dest = wave-uniform base + lane*16
#define GLL(gp, lp) __builtin_amdgcn_global_load_lds( \
    (const __attribute__((address_space(1))) void*)(gp), \
    (__attribute__((address_space(3))) void*)(lp), 16, 0, 0)

// ---------------------------------------------------------------------------
// Weight prep: f32 -> bf16 conversions + concatenations + bias builds.
// Element segments (8 elems / thread):
//  [0,        1048576): encw16  <- enc_att_w [512][2048]
//  [1048576,  3407872): wcat16  <- [hid_att_w;fbeta_w;w_hh] rows x 512
//  [3407872,  7602176): wihe16  <- w_ih[:, 512:] [2048][2048]
//  [7602176,  8650752): wihm16  <- w_ih[:, :512] [2048][512]
//  [8650752, 13770752): fc16    <- fc_w [10000][512]
//  [13770752,15867904): initW16 <- [init_h_w ; init_c_w] [1024][2048]
//  [15867904,15872512): biascat (f32 4608) = [hid_att_b; fbeta_b; 0]
//  [15872512,15874560): biasg   (f32 2048) = b_ih + b_hh
//  [15874560,15875584): biasInit(f32 1024) = [init_h_b ; init_c_b]
// ---------------------------------------------------------------------------
__global__ __launch_bounds__(256)
void kPrepW(const float* __restrict__ encw_s, const float* __restrict__ haw,
            const float* __restrict__ fbw, const float* __restrict__ whh,
            const float* __restrict__ wih, const float* __restrict__ fcw,
            const float* __restrict__ ihw, const float* __restrict__ icw,
            const float* __restrict__ hab, const float* __restrict__ fbb,
            const float* __restrict__ bih, const float* __restrict__ bhh,
            const float* __restrict__ ihb, const float* __restrict__ icb,
            short* __restrict__ encw_d, short* __restrict__ wcat_d,
            short* __restrict__ wihe_d, short* __restrict__ wihm_d,
            short* __restrict__ fc_d, short* __restrict__ initW_d,
            float* __restrict__ biascat, float* __restrict__ biasg,
            float* __restrict__ biasInit)
{
    long e = ((long)blockIdx.x * 256 + threadIdx.x) * 8;
    const float* sp = nullptr; short* dp = nullptr; long de = 0;
    if (e < 1048576)       { sp = &encw_s[e]; dp = encw_d; de = e; }
    else if (e < 3407872)  { long u = e - 1048576; long row = u >> 9, col = u & 511;
                             sp = (row < 512) ? &haw[row * 512 + col]
                                : (row < 2560) ? &fbw[(row - 512) * 512 + col]
                                               : &whh[(row - 2560) * 512 + col];
                             dp = wcat_d; de = u; }
    else if (e < 7602176)  { long u = e - 3407872; long row = u >> 11, col = u & 2047;
                             sp = &wih[row * 2560 + 512 + col]; dp = wihe_d; de = u; }
    else if (e < 8650752)  { long u = e - 7602176; long row = u >> 9, col = u & 511;
                             sp = &wih[row * 2560 + col]; dp = wihm_d; de = u; }
    else if (e < 13770752) { long u = e - 8650752; sp = &fcw[u]; dp = fc_d; de = u; }
    else if (e < 15867904) { long u = e - 13770752;
                             sp = (u < 1048576) ? &ihw[u] : &icw[u - 1048576];
                             dp = initW_d; de = u; }
    else if (e < 15872512) { long u = e - 15867904;
                             for (int j = 0; j < 8; ++j) { long w = u + j;
                                 biascat[w] = (w < 512) ? hab[w] : ((w < 2560) ? fbb[w - 512] : 0.f); }
                             return; }
    else if (e < 15874560) { long u = e - 15872512;
                             for (int j = 0; j < 8; ++j) biasg[u + j] = bih[u + j] + bhh[u + j];
                             return; }
    else if (e < 15875584) { long u = e - 15874560;
                             for (int j = 0; j < 8; ++j) { long w = u + j;
                                 biasInit[w] = (w < 512) ? ihb[w] : icb[w - 512]; }
                             return; }
    else return;
    union { short s[8]; int4v v; } u8;
    #pragma unroll
    for (int j = 0; j < 8; ++j) u8.s[j] = f2bf(sp[j]);
    *reinterpret_cast<int4v*>(&dp[de]) = u8.v;
}

// p-split mean partials + enc f32->bf16. grid (64, 8, 7): 28 rows per z-block.
template<int FULL>
__global__ __launch_bounds__(256)
void kMeanEnc(const float* __restrict__ enc, short* __restrict__ enc16,
              float* __restrict__ meanP)
{
    int b = blockIdx.x, kc = blockIdx.y, pz = blockIdx.z;
    int k = kc * 256 + threadIdx.x;
    const float* eb = &enc[((size_t)b * PP + pz * 28) * CENC + k];
    short* ob = &enc16[((size_t)b * PP + pz * 28) * CENC + k];
    float s0 = 0, s1 = 0, s2 = 0, s3 = 0;
    for (int p = 0; p < 28; p += 4) {
        float v0 = eb[(size_t)(p + 0) * CENC], v1 = eb[(size_t)(p + 1) * CENC];
        float v2 = eb[(size_t)(p + 2) * CENC], v3 = eb[(size_t)(p + 3) * CENC];
        s0 += v0; s1 += v1; s2 += v2; s3 += v3;
        if (FULL) {
            ob[(size_t)(p + 0) * CENC] = f2bf(v0); ob[(size_t)(p + 1) * CENC] = f2bf(v1);
            ob[(size_t)(p + 2) * CENC] = f2bf(v2); ob[(size_t)(p + 3) * CENC] = f2bf(v3);
        }
    }
    meanP[((size_t)pz * 64 + b) * 2048 + k] = (s0 + s1) + (s2 + s3);
}

// reduce 7 meanP partials -> mean16 bf16 [64][2048]
__global__ __launch_bounds__(256)
void kReduceMean(const float* __restrict__ meanP, short* __restrict__ mean16)
{
    int b = blockIdx.x, c0 = threadIdx.x * 8;
    const float inv = 1.0f / PP;
    union { short s[8]; int4v v; } u8;
    #pragma unroll
    for (int j = 0; j < 8; ++j) {
        float s = 0.f;
        #pragma unroll
        for (int pz = 0; pz < 7; ++pz) s += meanP[((size_t)pz * 64 + b) * 2048 + c0 + j];
        u8.s[j] = f2bf(s * inv);
    }
    *reinterpret_cast<int4v*>(&mean16[b * 2048 + c0]) = u8.v;
}

// embedding gather -> embA[r = t*64+b][512] bf16
__global__ __launch_bounds__(256)
void kEmbGather(const float* __restrict__ embw, const int* __restrict__ captions,
                short* __restrict__ embA)
{
    long e = ((long)blockIdx.x * 256 + threadIdx.x) * 8;
    int r = (int)(e >> 9), j = (int)(e & 511);
    int t = r >> 6, b = r & 63;
    int tok = captions[b * TT + t];
    const float* sp = &embw[(size_t)tok * EE + j];
    union { short s[8]; int4v v; } u8;
    #pragma unroll
    for (int q = 0; q < 8; ++q) u8.s[q] = f2bf(sp[q]);
    *reinterpret_cast<int4v*>(&embA[e]) = u8.v;
}

// ---------------------------------------------------------------------------
// MFMA bf16 GEMM: C[M,N] = A[M,K] @ W[N,K]^T. Tile 64x64, BK=64, 4 waves.
// bf16 staging via global_load_lds (linear LDS dest, inverse-XOR global src).
// AOP: 0 = A bf16 (gll); 1 = A f32 (register convert staging)
// WOP: 0 = plain row n0+r (bounds vs Ntot); 1 = gate-interleaved LSTM rows
// EOP: 0 = f32 +bias; 1 = bf16 +bias; 2 = pred (mask/remap);
//      3 = plain k-partials; 4 = gate-layout k-partials
// SWZ: 0 = (x,y,z)=(nb,mb,kz); 1 = att1 XCD swizzle; 2 = pred swizzle
// ---------------------------------------------------------------------------
template<int AOP, int WOP, int EOP, int SWZ>
__global__ __launch_bounds__(256)
void kGemm(const void* __restrict__ Ap, int lda, const short* __restrict__ W, int ldw,
           const float* __restrict__ bias, int Ntot,
           float* __restrict__ outF, int ldc, short* __restrict__ outB,
           int nk, const int* __restrict__ lengths)
{
    __shared__ short As[64 * 64];
    __shared__ short Ws[64 * 64];
    int nb, mb, kz;
    if (SWZ == 0) { nb = blockIdx.x; mb = blockIdx.y; kz = blockIdx.z; }
    else if (SWZ == 1) {  // att1: 1568 blocks, group 8 same-A n-blocks per XCD
        int j = blockIdx.x;
        if (j < 1536) { mb = (j >> 6) * 8 + (j & 7); nb = (j >> 3) & 7; }
        else          { int u = j - 1536; mb = 192 + (u >> 3); nb = u & 7; }
        kz = 0;
    } else {              // pred: 3040 blocks
        int j = blockIdx.x; int c = j & 7, s = j >> 3;
        mb = s % 19; int u = s / 19; nb = 8 * u + c; kz = 0;
        if (nb * 64 >= Ntot) return;
    }
    const int tid = threadIdx.x;
    const int m0 = mb * 64, n0 = nb * 64, k0 = kz * nk * 64;
    const int w = tid >> 6, l = tid & 63;
    floatx4 acc[4] = {};

    for (int ks = 0; ks < nk; ++ks) {
        int kt = k0 + ks * 64;
        // ---- stage A ----
        if (AOP == 0) {
            const short* A = (const short*)Ap;
            #pragma unroll
            for (int i = 0; i < 2; ++i) {
                int ii = w * 2 + i;                 // 8 x 1KB slots
                int row = ii * 8 + (l >> 3);
                int cg = l & 7;
                const short* gp = &A[(size_t)(m0 + row) * lda + kt + ((cg ^ (row & 7)) << 3)];
                GLL(gp, &As[ii * 512]);
            }
        } else {
            const float* A = (const float*)Ap;
            #pragma unroll
            for (int i = 0; i < 2; ++i) {
                int s = tid + i * 256, row = s >> 3, cg = s & 7;
                const float* sp = &A[(size_t)(m0 + row) * lda + kt + cg * 8];
                float4 a = *reinterpret_cast<const float4*>(sp);
                float4 b = *reinterpret_cast<const float4*>(sp + 4);
                union { short s[8]; int4v v; } u8;
                u8.s[0]=f2bf(a.x); u8.s[1]=f2bf(a.y); u8.s[2]=f2bf(a.z); u8.s[3]=f2bf(a.w);
                u8.s[4]=f2bf(b.x); u8.s[5]=f2bf(b.y); u8.s[6]=f2bf(b.z); u8.s[7]=f2bf(b.w);
                *reinterpret_cast<int4v*>(&As[row * 64 + ((cg ^ (row & 7)) << 3)]) = u8.v;
            }
        }
        // ---- stage W (gll) ----
        #pragma unroll
        for (int i = 0; i < 2; ++i) {
            int ii = w * 2 + i;
            int r = ii * 8 + (l >> 3);
            int cg = l & 7;
            int wr;
            if (WOP == 1) wr = 512 * (r >> 4) + 16 * nb + (r & 15);
            else          wr = n0 + r;
            if (WOP == 1 || wr < Ntot) {
                const short* gp = &W[(size_t)wr * ldw + kt + ((cg ^ (r & 7)) << 3)];
                GLL(gp, &Ws[ii * 512]);
            }
        }
        __syncthreads();
        // ---- MFMA ----
        #pragma unroll
        for (int kc = 0; kc < 2; ++kc) {
            int arow = 16 * w + (l & 15);
            int cg = 4 * kc + (l >> 4);
            short8 af = *reinterpret_cast<const short8*>(&As[arow * 64 + ((cg ^ (arow & 7)) << 3)]);
            #pragma unroll
            for (int q = 0; q < 4; ++q) {
                int wrow = 16 * q + (l & 15);
                short8 wf = *reinterpret_cast<const short8*>(&Ws[wrow * 64 + ((cg ^ (wrow & 7)) << 3)]);
                acc[q] = __builtin_amdgcn_mfma_f32_16x16x32_bf16(af, wf, acc[q], 0, 0, 0);
            }
        }
        __syncthreads();
    }
    // ---- epilogue ----
    int l4 = l >> 4, l15 = l & 15;
    #pragma unroll
    for (int q = 0; q < 4; ++q) {
        #pragma unroll
        for (int j = 0; j < 4; ++j) {
            int m = m0 + 16 * w + 4 * l4 + j;
            int n = n0 + 16 * q + l15;
            float val = acc[q][j];
            if (EOP == 0) {
                outF[(size_t)m * ldc + n] = val + bias[n];
            } else if (EOP == 1) {
                outB[(size_t)m * ldc + n] = f2bf(val + bias[n]);
            } else if (EOP == 2) {
                if (n < Ntot) {
                    int b = m & 63, tt = m >> 6;
                    bool act = tt < (lengths[b] - 1);
                    outF[((size_t)b * TM1 + tt) * VV + n] = act ? (val + bias[n]) : 0.f;
                }
            } else if (EOP == 3) {  // plain k-partials
                int mloc = m - m0;
                outF[((size_t)kz * 64 + mloc) * ldc + n] = val;
            } else {                // EOP == 4: gate-layout k-partials
                int col = 512 * q + (n0 >> 2) + l15;
                int mloc = m - m0;
                outF[((size_t)kz * 64 + mloc) * 2048 + col] = val;
            }
        }
    }
}

__global__ __launch_bounds__(256)
void kReduceHC(const float* __restrict__ Pc, const float* __restrict__ biasInit,
               float* __restrict__ hc, short* __restrict__ h16)
{
    int b = blockIdx.x, tid = threadIdx.x;
    for (int j = tid; j < 1024; j += 256) {
        float s = Pc[((size_t)0 * BB + b) * 1024 + j] + Pc[((size_t)1 * BB + b) * 1024 + j]
                + Pc[((size_t)2 * BB + b) * 1024 + j] + Pc[((size_t)3 * BB + b) * 1024 + j];
        s += biasInit[j];
        hc[b * 1024 + j] = s;
        if (j < 512) h16[b * 512 + j] = f2bf(s);
    }
}

// ---------------------------------------------------------------------------
// Fused Step B+C (512 blocks: b = blk&63, kc = blk>>6):
//   every block recomputes alpha for its b (cheap, deterministic, att1 L2-shared
//   across the 8 same-b blocks via blk&63 XCD mapping), then computes its
//   256-col awe slice + gate -> x16. out_alpha written by kc==0 blocks only.
// ---------------------------------------------------------------------------
template<int FULL>
__global__ __launch_bounds__(256)
void kStepBC(const short* __restrict__ att1, const float* __restrict__ P3h,
             const float* __restrict__ faw, const float* __restrict__ fab,
             const int* __restrict__ lengths, const void* __restrict__ encp,
             short* __restrict__ x16, float* __restrict__ alpha_out, int t)
{
    int blk = blockIdx.x, tid = threadIdx.x;
    int b = blk & 63, kc = blk >> 6;
    __shared__ float att2s[512];
    __shared__ float fw[512];
    __shared__ float es[PP];
    __shared__ float alps[PP];
    __shared__ float red[8];
    __shared__ float part[8][256];

    for (int a = tid; a < 512; a += 256) { att2s[a] = P3h[b * NCAT + a]; fw[a] = faw[a]; }
    __syncthreads();

    int wv = tid >> 6, lane = tid & 63;
    // e[p] = relu(att1[p]+att2).faw + fab
    for (int p = wv; p < PP; p += 4) {
        short8 v = *reinterpret_cast<const short8*>(&att1[((size_t)b * PP + p) * 512 + lane * 8]);
        float s = 0.f;
        #pragma unroll
        for (int j = 0; j < 8; ++j) {
            float x = bf2f(v[j]) + att2s[lane * 8 + j];
            s += fmaxf(x, 0.f) * fw[lane * 8 + j];
        }
        #pragma unroll
        for (int off = 32; off > 0; off >>= 1) s += __shfl_down(s, off, 64);
        if (lane == 0) es[p] = s + fab[0];
    }
    __syncthreads();
    // softmax over 196
    float m = -1e30f;
    for (int p = tid; p < PP; p += 256) m = fmaxf(m, es[p]);
    #pragma unroll
    for (int off = 32; off > 0; off >>= 1) m = fmaxf(m, __shfl_down(m, off, 64));
    if (lane == 0) red[wv] = m;
    __syncthreads();
    m = fmaxf(fmaxf(red[0], red[1]), fmaxf(red[2], red[3]));
    float ssum = 0.f;
    for (int p = tid; p < PP; p += 256) { float ev = __expf(es[p] - m); es[p] = ev; ssum += ev; }
    #pragma unroll
    for (int off = 32; off > 0; off >>= 1) ssum += __shfl_down(ssum, off, 64);
    if (lane == 0) red[4 + wv] = ssum;
    __syncthreads();
    float inv = 1.f / (red[4] + red[5] + red[6] + red[7]);
    bool active = t < (lengths[b] - 1);
    for (int p = tid; p < PP; p += 256) {
        float al = es[p] * inv;
        alps[p] = al;
        if (kc == 0)
            alpha_out[((size_t)b * TM1 + t) * PP + p] = active ? al : 0.f;
    }
    __syncthreads();

    // awe for 256-col slice [kc*256, kc*256+256)
    if (FULL) {
        const short* enc16 = (const short*)encp;
        int g = tid & 31, prow = tid >> 5;      // 8 cols/thread, 8 p-lanes
        int k0 = kc * 256 + g * 8;
        float acc[8] = {};
        for (int p = prow; p < PP; p += 8) {
            short8 v = *reinterpret_cast<const short8*>(&enc16[((size_t)b * PP + p) * CENC + k0]);
            float a_ = alps[p];
            #pragma unroll
            for (int j = 0; j < 8; ++j) acc[j] = fmaf(bf2f(v[j]), a_, acc[j]);
        }
        *reinterpret_cast<float4*>(&part[prow][g * 8])     = make_float4(acc[0], acc[1], acc[2], acc[3]);
        *reinterpret_cast<float4*>(&part[prow][g * 8 + 4]) = make_float4(acc[4], acc[5], acc[6], acc[7]);
        __syncthreads();
        int c = tid;
        float awe = 0.f;
        #pragma unroll
        for (int pr = 0; pr < 8; ++pr) awe += part[pr][c];
        int k = kc * 256 + c;
        float gate = 1.f / (1.f + __expf(-P3h[b * NCAT + 512 + k]));
        x16[(size_t)b * CENC + k] = f2bf(gate * awe);
    } else {
        const float* enc = (const float*)encp;
        int g = tid & 63, prow = tid >> 6;      // 4 cols/thread, 4 p-lanes
        int k0 = kc * 256 + g * 4;
        float acc[4] = {};
        for (int p = prow; p < PP; p += 4) {
            float4 v = *reinterpret_cast<const float4*>(&enc[((size_t)b * PP + p) * CENC + k0]);
            float a_ = alps[p];
            acc[0] = fmaf(v.x, a_, acc[0]); acc[1] = fmaf(v.y, a_, acc[1]);
            acc[2] = fmaf(v.z, a_, acc[2]); acc[3] = fmaf(v.w, a_, acc[3]);
        }
        *reinterpret_cast<float4*>(&part[prow][g * 4]) = make_float4(acc[0], acc[1], acc[2], acc[3]);
        __syncthreads();
        int c = tid;
        float awe = part[0][c] + part[1][c] + part[2][c] + part[3][c];
        int k = kc * 256 + c;
        float gate = 1.f / (1.f + __expf(-P3h[b * NCAT + 512 + k]));
        x16[(size_t)b * CENC + k] = f2bf(gate * awe);
    }
}

// ---------------------------------------------------------------------------
// Step D2: reduce gate partials (4 chunks) + emb part + Whh part; LSTM update.
// ---------------------------------------------------------------------------
__global__ __launch_bounds__(256)
void kStepD2(const float* __restrict__ Pg, const float* __restrict__ gates_emb,
             const float* __restrict__ P3h, float* __restrict__ hc,
             short* __restrict__ h16, short* __restrict__ allH, int t)
{
    int b = blockIdx.x, tid = threadIdx.x;
    for (int d = tid; d < 512; d += 256) {
        float g4[4];
        #pragma unroll
        for (int q = 0; q < 4; ++q) {
            int col = q * 512 + d;
            float s = gates_emb[((size_t)t * 64 + b) * 2048 + col] + P3h[b * NCAT + 2560 + col];
            #pragma unroll
            for (int kz = 0; kz < 4; ++kz) s += Pg[((size_t)kz * 64 + b) * 2048 + col];
            g4[q] = s;
        }
        float i_ = 1.f / (1.f + __expf(-g4[0]));
        float f_ = 1.f / (1.f + __expf(-g4[1]));
        float g_ = tanhf(g4[2]);
        float o_ = 1.f / (1.f + __expf(-g4[3]));
        float c_new = f_ * hc[b * 1024 + 512 + d] + i_ * g_;
        float h_new = o_ * tanhf(c_new);
        hc[b * 1024 + 512 + d] = c_new;
        hc[b * 1024 + d] = h_new;
        short hb = f2bf(h_new);
        h16[b * 512 + d] = hb;
        allH[((size_t)t * 64 + b) * 512 + d] = hb;
    }
}

extern "C" void kernel_launch(void* const* d_in, const int* in_sizes, int n_in,
                              void* d_out, int out_size, void* d_ws, size_t ws_size,
                              hipStream_t stream)
{
    const float* enc        = (const float*)d_in[0];
    const int*   captions   = (const int*)d_in[1];
    const int*   lengths    = (const int*)d_in[2];
    const float* enc_att_w  = (const float*)d_in[3];
    const float* enc_att_b  = (const float*)d_in[4];
    const float* hid_att_w  = (const float*)d_in[5];
    const float* hid_att_b  = (const float*)d_in[6];
    const float* full_att_w = (const float*)d_in[7];
    const float* full_att_b = (const float*)d_in[8];
    const float* embw       = (const float*)d_in[9];
    const float* w_ih       = (const float*)d_in[10];
    const float* w_hh       = (const float*)d_in[11];
    const float* b_ih       = (const float*)d_in[12];
    const float* b_hh       = (const float*)d_in[13];
    const float* init_h_w   = (const float*)d_in[14];
    const float* init_h_b   = (const float*)d_in[15];
    const float* init_c_w   = (const float*)d_in[16];
    const float* init_c_b   = (const float*)d_in[17];
    const float* fbeta_w    = (const float*)d_in[18];
    const float* fbeta_b    = (const float*)d_in[19];
    const float* fc_w       = (const float*)d_in[20];
    const float* fc_b       = (const float*)d_in[21];

    float* out_pred  = (float*)d_out;                        // [64][19][10000]
    float* out_alpha = out_pred + (size_t)BB * TM1 * VV;     // [64][19][196]

    // ---- scratch in d_out pred region (48.59MB <= 48.64MB, dead before pred)
    char* pr = (char*)d_out;
    short* att1_16   = (short*)pr;  pr += 12845056;  // live in loop
    float* gates_emb = (float*)pr;  pr += 9961472;   // live (overlaid at init time)
    short* wcat16    = (short*)pr;  pr += 4718592;   // live
    short* wihe16    = (short*)pr;  pr += 8388608;   // live
    float* biascat   = (float*)pr;  pr += 18432;     // live
    float* P3h       = (float*)pr;  pr += 1179648;   // live (loop)
    float* Pg        = (float*)pr;  pr += 2097152;   // live (loop)
    short* embA      = (short*)pr;  pr += 1245184;   // precompute only
    short* wihm16    = (short*)pr;  pr += 2097152;   // precompute only
    short* encw16    = (short*)pr;  pr += 2097152;   // dead after att1
    float* biasg     = (float*)pr;  pr += 8192;      // precompute only
    float* meanP     = (float*)pr;  pr += 3670016;   // dead after kReduceMean
    short* mean16    = (short*)pr;  pr += 262144;    // dead after init gemm

    // overlays (dead before their region's owner runs):
    short* initW16  = (short*)gates_emb;                 // 4.19MB, dead before gates_emb GEMM
    float* biasInit = (float*)((char*)gates_emb + 4194304);  // 4KB
    float* hcP      = P3h;                               // 1.0MB, dead before loop

    // ---- workspace
    char* wp = (char*)d_ws;
    float* hc    = (float*)wp;  wp += 262144;      // 64x1024 f32
    short* h16   = (short*)wp;  wp += 65536;       // 64x512 bf16
    short* x16   = (short*)wp;  wp += 262144;      // 64x2048 bf16
    short* fc16  = (short*)wp;  wp += 10240000;    // 10000x512 bf16
    short* allH  = (short*)wp;  wp += 1245184;     // 19x64x512 bf16
    short* enc16 = (short*)wp;  wp += 51380224;    // 64x196x2048 bf16 (optional)
    const bool full = ((size_t)(wp - (char*)d_ws) <= ws_size);

    // ---- precompute ----
    kPrepW<<<7752, 256, 0, stream>>>(enc_att_w, hid_att_w, fbeta_w, w_hh, w_ih, fc_w,
                                     init_h_w, init_c_w,
                                     hid_att_b, fbeta_b, b_ih, b_hh, init_h_b, init_c_b,
                                     encw16, wcat16, wihe16, wihm16, fc16, initW16,
                                     biascat, biasg, biasInit);
    if (full) kMeanEnc<1><<<dim3(64, 8, 7), 256, 0, stream>>>(enc, enc16, meanP);
    else      kMeanEnc<0><<<dim3(64, 8, 7), 256, 0, stream>>>(enc, enc16, meanP);
    kEmbGather<<<304, 256, 0, stream>>>(embw, captions, embA);
    kReduceMean<<<64, 256, 0, stream>>>(meanP, mean16);

    // h0|c0 partials = mean16 @ initW16^T  (MFMA, k-split x4) -> hcP
    kGemm<0, 0, 3, 0><<<dim3(16, 1, 4), 256, 0, stream>>>(mean16, CENC, initW16, CENC,
        nullptr, 1024, hcP, 1024, nullptr, 8, nullptr);
    kReduceHC<<<64, 256, 0, stream>>>(hcP, biasInit, hc, h16);

    // att1 = enc @ enc_att_w^T + b -> bf16 [12544][512]
    if (full)
        kGemm<0, 0, 1, 1><<<1568, 256, 0, stream>>>(enc16, CENC, encw16, CENC,
            enc_att_b, 512, nullptr, 512, att1_16, 32, nullptr);
    else
        kGemm<1, 0, 1, 1><<<1568, 256, 0, stream>>>(enc, CENC, encw16, CENC,
            enc_att_b, 512, nullptr, 512, att1_16, 32, nullptr);

    // gates_emb = embA @ W_ih[:, :512]^T + (b_ih + b_hh)  -> f32 [1216][2048]
    // (overwrites the initW16/biasInit overlay -- they are dead by now)
    kGemm<0, 0, 0, 0><<<dim3(32, 19, 1), 256, 0, stream>>>(embA, 512, wihm16, 512,
        biasg, 2048, gates_emb, 2048, nullptr, 8, nullptr);

    // ---- sequential decode: 4 kernels per step ----
    for (int t = 0; t < TM1; ++t) {
        // P3h = h @ [hid_att_w ; fbeta_w ; W_hh]^T + biascat  -> [64][4608]
        kGemm<0, 0, 0, 0><<<dim3(72, 1, 1), 256, 0, stream>>>(h16, 512, wcat16, 512,
            biascat, NCAT, P3h, NCAT, nullptr, 8, nullptr);

        if (full) kStepBC<1><<<512, 256, 0, stream>>>(att1_16, P3h, full_att_w,
            full_att_b, lengths, enc16, x16, out_alpha, t);
        else      kStepBC<0><<<512, 256, 0, stream>>>(att1_16, P3h, full_att_w,
            full_att_b, lengths, enc, x16, out_alpha, t);

        // gate partials: x @ W_ih[:, 512:]^T (gate-interleaved rows), k-split x4
        kGemm<0, 1, 4, 0><<<dim3(32, 1, 4), 256, 0, stream>>>(x16, CENC, wihe16, CENC,
            nullptr, 2048, Pg, 2048, nullptr, 8, nullptr);

        kStepD2<<<64, 256, 0, stream>>>(Pg, gates_emb, P3h, hc, h16, allH, t);
    }

    // ---- pred = allH @ fc_w^T + fc_b (masked, remapped) ----
    kGemm<0, 0, 2, 2><<<3040, 256, 0, stream>>>(allH, 512, fc16, 512,
        fc_b, VV, out_pred, VV, nullptr, 8, lengths);
}